// Round 5
// baseline (947.877 us; speedup 1.0000x reference)
//
#include <hip/hip_runtime.h>
#include <math.h>

#define N_NODES 20000
#define N_EDGES 320000
#define N_GRAPHS 64
#define D_IN 1280
#define D_H 512
#define D_FC 1024
#define OUT_DIMS 5000

typedef unsigned short ushort_t;
typedef short bf16x8 __attribute__((ext_vector_type(8)));
typedef float f32x4 __attribute__((ext_vector_type(4)));

__device__ __forceinline__ ushort_t f2b(float x) {
    unsigned u = __float_as_uint(x);
    unsigned r = (u + 0x7FFFu + ((u >> 16) & 1u)) >> 16;  // RNE
    return (ushort_t)r;
}

// ============ bf16 MFMA GEMM: C[M,N] = A[M,K] @ BT[N,K]^T, C in bf16 ============
// 128x128 block tile, 4 waves, 64x64/wave as 4x4 grid of 16x16x32 MFMA.
// LDS tiles stored [dim][k], row stride 40 shorts (2-way bank aliasing = free).
// A_IS_F32: stage fp32 A with inline bf16 conversion; else A is bf16.
template <bool A_IS_F32>
__global__ __launch_bounds__(256) void mfma_gemm(const void* __restrict__ Ap,
                                                 const ushort_t* __restrict__ BT,
                                                 ushort_t* __restrict__ C,
                                                 int M, int N, int K) {
    __shared__ ushort_t As[128 * 40];
    __shared__ ushort_t Bs[128 * 40];
    const int t = threadIdx.x;
    const int lane = t & 63, wave = t >> 6;
    const int wrow = (wave >> 1) * 64, wcol = (wave & 1) * 64;
    const int lo = lane & 15, quad = lane >> 4;
    const int rowBase = blockIdx.y * 128;
    const int colBase = blockIdx.x * 128;

    f32x4 acc[4][4] = {};

    for (int k0 = 0; k0 < K; k0 += 32) {
        __syncthreads();
#pragma unroll
        for (int i = 0; i < 2; ++i) {  // stage A: 512 slots of 8 bf16
            int s = t + i * 256;
            int r = s >> 2, c8 = (s & 3) * 8;
            int gr = rowBase + r;
            ushort_t* dp = &As[r * 40 + c8];
            if (A_IS_F32) {
                const float* A = (const float*)Ap;
                float4 v0 = {0.f, 0.f, 0.f, 0.f}, v1 = {0.f, 0.f, 0.f, 0.f};
                if (gr < M) {
                    const float* p = A + (size_t)gr * K + k0 + c8;
                    v0 = *(const float4*)p;
                    v1 = *(const float4*)(p + 4);
                }
                ushort_t w[8] = {f2b(v0.x), f2b(v0.y), f2b(v0.z), f2b(v0.w),
                                 f2b(v1.x), f2b(v1.y), f2b(v1.z), f2b(v1.w)};
                *(uint4*)dp = *(uint4*)w;
            } else {
                const ushort_t* A = (const ushort_t*)Ap;
                uint4 v = {0u, 0u, 0u, 0u};
                if (gr < M) v = *(const uint4*)(A + (size_t)gr * K + k0 + c8);
                *(uint4*)dp = v;
            }
        }
#pragma unroll
        for (int i = 0; i < 2; ++i) {  // stage B (bf16, pre-transposed)
            int s = t + i * 256;
            int n = s >> 2, c8 = (s & 3) * 8;
            int gc = colBase + n;
            uint4 v = {0u, 0u, 0u, 0u};
            if (gc < N) v = *(const uint4*)(BT + (size_t)gc * K + k0 + c8);
            *(uint4*)&Bs[n * 40 + c8] = v;
        }
        __syncthreads();
        bf16x8 af[4], bfr[4];
#pragma unroll
        for (int i = 0; i < 4; ++i)
            af[i] = *(const bf16x8*)&As[(wrow + i * 16 + lo) * 40 + quad * 8];
#pragma unroll
        for (int j = 0; j < 4; ++j)
            bfr[j] = *(const bf16x8*)&Bs[(wcol + j * 16 + lo) * 40 + quad * 8];
#pragma unroll
        for (int i = 0; i < 4; ++i)
#pragma unroll
            for (int j = 0; j < 4; ++j)
                acc[i][j] = __builtin_amdgcn_mfma_f32_16x16x32_bf16(af[i], bfr[j], acc[i][j], 0, 0, 0);
    }
    // epilogue: C/D layout col=lane&15, row=quad*4+reg ; store bf16
#pragma unroll
    for (int i = 0; i < 4; ++i) {
        int row0 = rowBase + wrow + i * 16 + quad * 4;
#pragma unroll
        for (int j = 0; j < 4; ++j) {
            int col = colBase + wcol + j * 16 + lo;
            if (col >= N) continue;
#pragma unroll
            for (int r = 0; r < 4; ++r) {
                int row = row0 + r;
                if (row < M) C[(size_t)row * N + col] = f2b(acc[i][j][r]);
            }
        }
    }
}

// transpose + fp32->bf16: WT[n*K+k] = bf16(W[k*N+n])
__global__ void wt_cvt_transpose(const float* __restrict__ W, ushort_t* __restrict__ WT,
                                 int K, int N) {
    int i = blockIdx.x * blockDim.x + threadIdx.x;
    if (i >= N * K) return;
    int n = i / K, k = i - n * K;
    WT[i] = f2b(W[(size_t)k * N + n]);
}

// ---------------- fp32 tiled GEMM (FC head) ----------------
__global__ __launch_bounds__(256) void gemm_tile(const float* __restrict__ A,
                                                 const float* __restrict__ B,
                                                 float* __restrict__ C,
                                                 int M, int N, int K) {
    __shared__ float As[16][64];
    __shared__ float Bs[16][64];
    const int t = threadIdx.x;
    const int tx = t & 15, ty = t >> 4;
    const int rowBase = blockIdx.y * 64;
    const int colBase = blockIdx.x * 64;
    float acc[4][4] = {};
    for (int k0 = 0; k0 < K; k0 += 16) {
#pragma unroll
        for (int i = 0; i < 4; ++i) {
            int idx = t + i * 256;
            int row = idx >> 4, kk = idx & 15;
            int gr = rowBase + row;
            As[kk][row] = (gr < M) ? A[(size_t)gr * K + k0 + kk] : 0.f;
        }
#pragma unroll
        for (int i = 0; i < 4; ++i) {
            int idx = t + i * 256;
            int kk = idx >> 6, col = idx & 63;
            int gc = colBase + col;
            Bs[kk][col] = (gc < N) ? B[(size_t)(k0 + kk) * N + gc] : 0.f;
        }
        __syncthreads();
#pragma unroll
        for (int kk = 0; kk < 16; ++kk) {
            float a[4], b[4];
#pragma unroll
            for (int i = 0; i < 4; ++i) a[i] = As[kk][ty * 4 + i];
#pragma unroll
            for (int j = 0; j < 4; ++j) b[j] = Bs[kk][tx * 4 + j];
#pragma unroll
            for (int i = 0; i < 4; ++i)
#pragma unroll
                for (int j = 0; j < 4; ++j) acc[i][j] = fmaf(a[i], b[j], acc[i][j]);
        }
        __syncthreads();
    }
#pragma unroll
    for (int i = 0; i < 4; ++i) {
        int gr = rowBase + ty * 4 + i;
        if (gr >= M) continue;
#pragma unroll
        for (int j = 0; j < 4; ++j) {
            int gc = colBase + tx * 4 + j;
            if (gc < N) C[(size_t)gr * N + gc] = acc[i][j];
        }
    }
}

// ---------------- CSR construction ----------------
__global__ void hist_deg(const int* __restrict__ dst, int* __restrict__ cnt) {
    int e = blockIdx.x * blockDim.x + threadIdx.x;
    if (e < N_EDGES) atomicAdd(cnt + dst[e], 1);
}

__global__ void compute_dinv(const int* __restrict__ cnt, float* __restrict__ dinv) {
    int v = blockIdx.x * blockDim.x + threadIdx.x;
    if (v < N_NODES) dinv[v] = rsqrtf((float)cnt[v] + 1.0f);  // +1 self-loop
}

__global__ __launch_bounds__(256) void scan_rowptr(const int* __restrict__ cnt,
                                                   int* __restrict__ rowptr) {
    __shared__ int sums[256];
    const int t = threadIdx.x;
    const int CH = (N_NODES + 255) / 256;
    const int base = t * CH;
    int s = 0;
    for (int i = 0; i < CH; ++i) {
        int v = base + i;
        if (v < N_NODES) s += cnt[v];
    }
    sums[t] = s;
    __syncthreads();
    for (int off = 1; off < 256; off <<= 1) {
        int y = (t >= off) ? sums[t - off] : 0;
        __syncthreads();
        sums[t] += y;
        __syncthreads();
    }
    int run = sums[t] - s;
    for (int i = 0; i < CH; ++i) {
        int v = base + i;
        if (v < N_NODES) {
            rowptr[v] = run;
            run += cnt[v];
        }
    }
    if (t == 255) rowptr[N_NODES] = run;
}

__global__ void fill_csr(const int* __restrict__ src, const int* __restrict__ dst,
                         const int* __restrict__ rowptr, int* __restrict__ cursor,
                         int* __restrict__ col) {
    int e = blockIdx.x * blockDim.x + threadIdx.x;
    if (e < N_EDGES) {
        int d = dst[e];
        int p = rowptr[d] + atomicAdd(cursor + d, 1);
        col[p] = src[e];
    }
}

// ---------------- bf16 gather-aggregate ----------------
// one 64-thread wave per node; thread covers 8 feats (16 B); fp32 accum
__device__ __forceinline__ void bf8_fma(uint4 v, float c, float* acc) {
    unsigned a[4] = {v.x, v.y, v.z, v.w};
#pragma unroll
    for (int i = 0; i < 4; ++i) {
        float lo = __uint_as_float(a[i] << 16);
        float hi = __uint_as_float(a[i] & 0xFFFF0000u);
        acc[2 * i]     = fmaf(lo, c, acc[2 * i]);
        acc[2 * i + 1] = fmaf(hi, c, acc[2 * i + 1]);
    }
}

__device__ __forceinline__ void agg_node_bf16(const ushort_t* __restrict__ H,
                                              const int* __restrict__ rowptr,
                                              const int* __restrict__ col,
                                              const float* __restrict__ dinv,
                                              const float* __restrict__ bias,
                                              int v, int f, float* r) {
    const int beg = rowptr[v], end = rowptr[v + 1];
    const float dv = dinv[v];
    float acc[8] = {};
    int j = beg;
    for (; j + 1 < end; j += 2) {
        int s0 = col[j], s1 = col[j + 1];
        float c0 = dinv[s0] * dv, c1 = dinv[s1] * dv;
        uint4 h0 = *(const uint4*)(H + (size_t)s0 * D_H + f);
        uint4 h1 = *(const uint4*)(H + (size_t)s1 * D_H + f);
        bf8_fma(h0, c0, acc);
        bf8_fma(h1, c1, acc);
    }
    if (j < end) {
        int s0 = col[j];
        float c0 = dinv[s0] * dv;
        uint4 h0 = *(const uint4*)(H + (size_t)s0 * D_H + f);
        bf8_fma(h0, c0, acc);
    }
    uint4 hv = *(const uint4*)(H + (size_t)v * D_H + f);
    bf8_fma(hv, dv * dv, acc);  // self-loop
    float4 b0 = *(const float4*)(bias + f);
    float4 b1 = *(const float4*)(bias + f + 4);
    r[0] = fmaxf(acc[0] + b0.x, 0.f);
    r[1] = fmaxf(acc[1] + b0.y, 0.f);
    r[2] = fmaxf(acc[2] + b0.z, 0.f);
    r[3] = fmaxf(acc[3] + b0.w, 0.f);
    r[4] = fmaxf(acc[4] + b1.x, 0.f);
    r[5] = fmaxf(acc[5] + b1.y, 0.f);
    r[6] = fmaxf(acc[6] + b1.z, 0.f);
    r[7] = fmaxf(acc[7] + b1.w, 0.f);
}

// conv1 aggregation -> bf16 h1 (feeds conv2 MFMA GEMM)
__global__ __launch_bounds__(64) void gather_agg_relu_bf16(const ushort_t* __restrict__ H,
                                                           const int* __restrict__ rowptr,
                                                           const int* __restrict__ col,
                                                           const float* __restrict__ dinv,
                                                           const float* __restrict__ bias,
                                                           ushort_t* __restrict__ out) {
    const int v = blockIdx.x;
    const int f = threadIdx.x * 8;
    float r[8];
    agg_node_bf16(H, rowptr, col, dinv, bias, v, f, r);
    ushort_t o[8];
#pragma unroll
    for (int i = 0; i < 8; ++i) o[i] = f2b(r[i]);
    *(uint4*)(out + (size_t)v * D_H + f) = *(uint4*)o;
}

// conv2 aggregation fused with global max pool (values >=0, gbuf init 0)
__global__ __launch_bounds__(64) void gather_agg_pool(const ushort_t* __restrict__ H,
                                                      const int* __restrict__ rowptr,
                                                      const int* __restrict__ col,
                                                      const float* __restrict__ dinv,
                                                      const float* __restrict__ bias,
                                                      const int* __restrict__ batch,
                                                      float* __restrict__ gbuf) {
    const int v = blockIdx.x;
    const int f = threadIdx.x * 8;
    float r[8];
    agg_node_bf16(H, rowptr, col, dinv, bias, v, f, r);
    int gr = batch[v];
    int* o = (int*)(gbuf + (size_t)gr * D_H + f);
#pragma unroll
    for (int i = 0; i < 8; ++i) atomicMax(o + i, __float_as_int(r[i]));
}

__global__ void bias_relu(float* __restrict__ x, const float* __restrict__ b, int total, int N) {
    int i = blockIdx.x * blockDim.x + threadIdx.x;
    if (i < total) x[i] = fmaxf(x[i] + b[i % N], 0.f);
}

__global__ void bn_sigmoid(const float* __restrict__ logits, const float* __restrict__ b2,
                           const float* __restrict__ gamma, const float* __restrict__ beta,
                           float* __restrict__ out) {
    int i = blockIdx.x * blockDim.x + threadIdx.x;
    if (i >= N_GRAPHS * OUT_DIMS) return;
    int c = i % OUT_DIMS;
    const float s = 0.9999950000374997f;  // 1/sqrt(1+1e-5)
    float z = (logits[i] + b2[c]) * (gamma[c] * s) + beta[c];
    out[i] = 1.f / (1.f + expf(-z));
}

extern "C" void kernel_launch(void* const* d_in, const int* in_sizes, int n_in,
                              void* d_out, int out_size, void* d_ws, size_t ws_size,
                              hipStream_t stream) {
    const float* x     = (const float*)d_in[0];
    const int*   ei    = (const int*)d_in[1];    // int64 in reference -> int32 on device
    const int*   batch = (const int*)d_in[2];
    const float* Wg1   = (const float*)d_in[3];
    const float* bg1   = (const float*)d_in[4];
    const float* Wg2   = (const float*)d_in[5];
    const float* bg2   = (const float*)d_in[6];
    const float* W1    = (const float*)d_in[7];
    const float* b1    = (const float*)d_in[8];
    const float* W2    = (const float*)d_in[9];
    const float* b2    = (const float*)d_in[10];
    const float* gamma = (const float*)d_in[11];
    const float* beta  = (const float*)d_in[12];
    const int* src = ei;
    const int* dst = ei + N_EDGES;
    float* out = (float*)d_out;

    // workspace layout (all 16B-aligned)
    ushort_t* hpre   = (ushort_t*)d_ws;                        // [N_NODES, D_H] bf16 (conv GEMM out)
    ushort_t* h1b    = hpre + (size_t)N_NODES * D_H;           // [N_NODES, D_H] bf16
    ushort_t* w1t    = h1b + (size_t)N_NODES * D_H;            // [D_H, D_IN] bf16 (Wg1^T)
    ushort_t* w2t    = w1t + (size_t)D_H * D_IN;               // [D_H, D_H] bf16 (Wg2^T)
    float*    dinv   = (float*)(w2t + (size_t)D_H * D_H);      // [N_NODES]
    float*    gbuf   = dinv + N_NODES;                         // [N_GRAPHS, D_H]
    float*    fc1o   = gbuf + N_GRAPHS * D_H;                  // [N_GRAPHS, D_FC]
    float*    logits = fc1o + N_GRAPHS * D_FC;                 // [N_GRAPHS, OUT_DIMS]
    int*      cnt    = (int*)(logits + N_GRAPHS * OUT_DIMS);   // [N_NODES]
    int*      rowptr = cnt + N_NODES;                          // [N_NODES+1]
    int*      cursor = rowptr + N_NODES + 1;                   // [N_NODES]
    int*      colidx = cursor + N_NODES;                       // [N_EDGES]

    // ---- CSR build (by dst) + dinv + weight transpose/convert ----
    hipMemsetAsync(cnt, 0, N_NODES * sizeof(int), stream);
    hipMemsetAsync(cursor, 0, N_NODES * sizeof(int), stream);
    hipMemsetAsync(gbuf, 0, N_GRAPHS * D_H * sizeof(float), stream);
    hist_deg<<<(N_EDGES + 255) / 256, 256, 0, stream>>>(dst, cnt);
    compute_dinv<<<(N_NODES + 255) / 256, 256, 0, stream>>>(cnt, dinv);
    scan_rowptr<<<1, 256, 0, stream>>>(cnt, rowptr);
    fill_csr<<<(N_EDGES + 255) / 256, 256, 0, stream>>>(src, dst, rowptr, cursor, colidx);
    wt_cvt_transpose<<<(D_H * D_IN + 255) / 256, 256, 0, stream>>>(Wg1, w1t, D_IN, D_H);
    wt_cvt_transpose<<<(D_H * D_H + 255) / 256, 256, 0, stream>>>(Wg2, w2t, D_H, D_H);

    dim3 gconv((D_H + 127) / 128, (N_NODES + 127) / 128);  // (4, 157)

    // conv1: hpre = bf16(x @ Wg1) ; gather+relu -> h1b (bf16)
    mfma_gemm<true><<<gconv, 256, 0, stream>>>(x, w1t, hpre, N_NODES, D_H, D_IN);
    gather_agg_relu_bf16<<<N_NODES, 64, 0, stream>>>(hpre, rowptr, colidx, dinv, bg1, h1b);

    // conv2: hpre = bf16(h1b @ Wg2) ; gather + relu + fused max-pool -> gbuf
    mfma_gemm<false><<<gconv, 256, 0, stream>>>(h1b, w2t, hpre, N_NODES, D_H, D_H);
    gather_agg_pool<<<N_NODES, 64, 0, stream>>>(hpre, rowptr, colidx, dinv, bg2, batch, gbuf);

    // fc1: [64,512]@[512,1024] + b1, relu
    dim3 gfc1((D_FC + 63) / 64, (N_GRAPHS + 63) / 64);
    gemm_tile<<<gfc1, 256, 0, stream>>>(gbuf, W1, fc1o, N_GRAPHS, D_FC, D_H);
    bias_relu<<<(N_GRAPHS * D_FC + 255) / 256, 256, 0, stream>>>(fc1o, b1, N_GRAPHS * D_FC, D_FC);

    // fc2: [64,1024]@[1024,5000] -> logits ; BN + sigmoid -> out
    dim3 gfc2((OUT_DIMS + 63) / 64, (N_GRAPHS + 63) / 64);
    gemm_tile<<<gfc2, 256, 0, stream>>>(fc1o, W2, logits, N_GRAPHS, OUT_DIMS, D_FC);
    bn_sigmoid<<<(N_GRAPHS * OUT_DIMS + 255) / 256, 256, 0, stream>>>(logits, b2, gamma, beta, out);
}

// Round 6
// 724.305 us; speedup vs baseline: 1.3087x; 1.3087x over previous
//
#include <hip/hip_runtime.h>
#include <math.h>

#define N_NODES 20000
#define N_EDGES 320000
#define N_GRAPHS 64
#define D_IN 1280
#define D_H 512
#define D_FC 1024
#define OUT_DIMS 5000

typedef unsigned short ushort_t;
typedef short bf16x8 __attribute__((ext_vector_type(8)));
typedef float f32x4 __attribute__((ext_vector_type(4)));

__device__ __forceinline__ ushort_t f2b(float x) {
    unsigned u = __float_as_uint(x);
    unsigned r = (u + 0x7FFFu + ((u >> 16) & 1u)) >> 16;  // RNE
    return (ushort_t)r;
}

// ============ bf16 MFMA GEMM: C[M,N] = A[M,K] @ BT[N,K]^T, C in bf16 ============
// 128x128 block tile, 4 waves, 64x64/wave as 4x4 grid of 16x16x32 MFMA.
// LDS tiles stored [dim][k], row stride 40 shorts (2-way bank aliasing = free).
// A_IS_F32: stage fp32 A with inline bf16 conversion; else A is bf16.
template <bool A_IS_F32>
__global__ __launch_bounds__(256) void mfma_gemm(const void* __restrict__ Ap,
                                                 const ushort_t* __restrict__ BT,
                                                 ushort_t* __restrict__ C,
                                                 int M, int N, int K) {
    __shared__ ushort_t As[128 * 40];
    __shared__ ushort_t Bs[128 * 40];
    const int t = threadIdx.x;
    const int lane = t & 63, wave = t >> 6;
    const int wrow = (wave >> 1) * 64, wcol = (wave & 1) * 64;
    const int lo = lane & 15, quad = lane >> 4;
    const int rowBase = blockIdx.y * 128;
    const int colBase = blockIdx.x * 128;

    f32x4 acc[4][4] = {};

    for (int k0 = 0; k0 < K; k0 += 32) {
        __syncthreads();
#pragma unroll
        for (int i = 0; i < 2; ++i) {  // stage A: 512 slots of 8 bf16
            int s = t + i * 256;
            int r = s >> 2, c8 = (s & 3) * 8;
            int gr = rowBase + r;
            ushort_t* dp = &As[r * 40 + c8];
            if (A_IS_F32) {
                const float* A = (const float*)Ap;
                float4 v0 = {0.f, 0.f, 0.f, 0.f}, v1 = {0.f, 0.f, 0.f, 0.f};
                if (gr < M) {
                    const float* p = A + (size_t)gr * K + k0 + c8;
                    v0 = *(const float4*)p;
                    v1 = *(const float4*)(p + 4);
                }
                ushort_t w[8] = {f2b(v0.x), f2b(v0.y), f2b(v0.z), f2b(v0.w),
                                 f2b(v1.x), f2b(v1.y), f2b(v1.z), f2b(v1.w)};
                *(uint4*)dp = *(uint4*)w;
            } else {
                const ushort_t* A = (const ushort_t*)Ap;
                uint4 v = {0u, 0u, 0u, 0u};
                if (gr < M) v = *(const uint4*)(A + (size_t)gr * K + k0 + c8);
                *(uint4*)dp = v;
            }
        }
#pragma unroll
        for (int i = 0; i < 2; ++i) {  // stage B (bf16, pre-transposed)
            int s = t + i * 256;
            int n = s >> 2, c8 = (s & 3) * 8;
            int gc = colBase + n;
            uint4 v = {0u, 0u, 0u, 0u};
            if (gc < N) v = *(const uint4*)(BT + (size_t)gc * K + k0 + c8);
            *(uint4*)&Bs[n * 40 + c8] = v;
        }
        __syncthreads();
        bf16x8 af[4], bfr[4];
#pragma unroll
        for (int i = 0; i < 4; ++i)
            af[i] = *(const bf16x8*)&As[(wrow + i * 16 + lo) * 40 + quad * 8];
#pragma unroll
        for (int j = 0; j < 4; ++j)
            bfr[j] = *(const bf16x8*)&Bs[(wcol + j * 16 + lo) * 40 + quad * 8];
#pragma unroll
        for (int i = 0; i < 4; ++i)
#pragma unroll
            for (int j = 0; j < 4; ++j)
                acc[i][j] = __builtin_amdgcn_mfma_f32_16x16x32_bf16(af[i], bfr[j], acc[i][j], 0, 0, 0);
    }
    // epilogue: C/D layout col=lane&15, row=quad*4+reg ; store bf16
#pragma unroll
    for (int i = 0; i < 4; ++i) {
        int row0 = rowBase + wrow + i * 16 + quad * 4;
#pragma unroll
        for (int j = 0; j < 4; ++j) {
            int col = colBase + wcol + j * 16 + lo;
            if (col >= N) continue;
#pragma unroll
            for (int r = 0; r < 4; ++r) {
                int row = row0 + r;
                if (row < M) C[(size_t)row * N + col] = f2b(acc[i][j][r]);
            }
        }
    }
}

// transpose + fp32->bf16: WT[n*K+k] = bf16(W[k*N+n])
__global__ void wt_cvt_transpose(const float* __restrict__ W, ushort_t* __restrict__ WT,
                                 int K, int N) {
    int i = blockIdx.x * blockDim.x + threadIdx.x;
    if (i >= N * K) return;
    int n = i / K, k = i - n * K;
    WT[i] = f2b(W[(size_t)k * N + n]);
}

// ---------------- fp32 tiled GEMM (FC head) ----------------
__global__ __launch_bounds__(256) void gemm_tile(const float* __restrict__ A,
                                                 const float* __restrict__ B,
                                                 float* __restrict__ C,
                                                 int M, int N, int K) {
    __shared__ float As[16][64];
    __shared__ float Bs[16][64];
    const int t = threadIdx.x;
    const int tx = t & 15, ty = t >> 4;
    const int rowBase = blockIdx.y * 64;
    const int colBase = blockIdx.x * 64;
    float acc[4][4] = {};
    for (int k0 = 0; k0 < K; k0 += 16) {
#pragma unroll
        for (int i = 0; i < 4; ++i) {
            int idx = t + i * 256;
            int row = idx >> 4, kk = idx & 15;
            int gr = rowBase + row;
            As[kk][row] = (gr < M) ? A[(size_t)gr * K + k0 + kk] : 0.f;
        }
#pragma unroll
        for (int i = 0; i < 4; ++i) {
            int idx = t + i * 256;
            int kk = idx >> 6, col = idx & 63;
            int gc = colBase + col;
            Bs[kk][col] = (gc < N) ? B[(size_t)(k0 + kk) * N + gc] : 0.f;
        }
        __syncthreads();
#pragma unroll
        for (int kk = 0; kk < 16; ++kk) {
            float a[4], b[4];
#pragma unroll
            for (int i = 0; i < 4; ++i) a[i] = As[kk][ty * 4 + i];
#pragma unroll
            for (int j = 0; j < 4; ++j) b[j] = Bs[kk][tx * 4 + j];
#pragma unroll
            for (int i = 0; i < 4; ++i)
#pragma unroll
                for (int j = 0; j < 4; ++j) acc[i][j] = fmaf(a[i], b[j], acc[i][j]);
        }
        __syncthreads();
    }
#pragma unroll
    for (int i = 0; i < 4; ++i) {
        int gr = rowBase + ty * 4 + i;
        if (gr >= M) continue;
#pragma unroll
        for (int j = 0; j < 4; ++j) {
            int gc = colBase + tx * 4 + j;
            if (gc < N) C[(size_t)gr * N + gc] = acc[i][j];
        }
    }
}

// ---------------- CSR construction ----------------
__global__ void hist_deg(const int* __restrict__ dst, int* __restrict__ cnt) {
    int e = blockIdx.x * blockDim.x + threadIdx.x;
    if (e < N_EDGES) atomicAdd(cnt + dst[e], 1);
}

__global__ void compute_dinv(const int* __restrict__ cnt, float* __restrict__ dinv) {
    int v = blockIdx.x * blockDim.x + threadIdx.x;
    if (v < N_NODES) dinv[v] = rsqrtf((float)cnt[v] + 1.0f);  // +1 self-loop
}

__global__ __launch_bounds__(256) void scan_rowptr(const int* __restrict__ cnt,
                                                   int* __restrict__ rowptr) {
    __shared__ int sums[256];
    const int t = threadIdx.x;
    const int CH = (N_NODES + 255) / 256;
    const int base = t * CH;
    int s = 0;
    for (int i = 0; i < CH; ++i) {
        int v = base + i;
        if (v < N_NODES) s += cnt[v];
    }
    sums[t] = s;
    __syncthreads();
    for (int off = 1; off < 256; off <<= 1) {
        int y = (t >= off) ? sums[t - off] : 0;
        __syncthreads();
        sums[t] += y;
        __syncthreads();
    }
    int run = sums[t] - s;
    for (int i = 0; i < CH; ++i) {
        int v = base + i;
        if (v < N_NODES) {
            rowptr[v] = run;
            run += cnt[v];
        }
    }
    if (t == 255) rowptr[N_NODES] = run;
}

__global__ void fill_csr(const int* __restrict__ src, const int* __restrict__ dst,
                         const int* __restrict__ rowptr, int* __restrict__ cursor,
                         int* __restrict__ col) {
    int e = blockIdx.x * blockDim.x + threadIdx.x;
    if (e < N_EDGES) {
        int d = dst[e];
        int p = rowptr[d] + atomicAdd(cursor + d, 1);
        col[p] = src[e];
    }
}

// ---------------- bf16 gather-aggregate ----------------
// one 64-thread wave per node; thread covers 8 feats (16 B); fp32 accum;
// 4-deep edge unroll for memory-level parallelism (latency-bound kernel)
__device__ __forceinline__ void bf8_fma(uint4 v, float c, float* acc) {
    unsigned a[4] = {v.x, v.y, v.z, v.w};
#pragma unroll
    for (int i = 0; i < 4; ++i) {
        float lo = __uint_as_float(a[i] << 16);
        float hi = __uint_as_float(a[i] & 0xFFFF0000u);
        acc[2 * i]     = fmaf(lo, c, acc[2 * i]);
        acc[2 * i + 1] = fmaf(hi, c, acc[2 * i + 1]);
    }
}

__device__ __forceinline__ void agg_node_bf16(const ushort_t* __restrict__ H,
                                              const int* __restrict__ rowptr,
                                              const int* __restrict__ col,
                                              const float* __restrict__ dinv,
                                              const float* __restrict__ bias,
                                              int v, int f, float* r) {
    const int beg = rowptr[v], end = rowptr[v + 1];
    const float dv = dinv[v];
    float acc[8] = {};
    int j = beg;
    for (; j + 3 < end; j += 4) {
        int s0 = col[j], s1 = col[j + 1], s2 = col[j + 2], s3 = col[j + 3];
        float c0 = dinv[s0] * dv, c1 = dinv[s1] * dv;
        float c2 = dinv[s2] * dv, c3 = dinv[s3] * dv;
        uint4 h0 = *(const uint4*)(H + (size_t)s0 * D_H + f);
        uint4 h1 = *(const uint4*)(H + (size_t)s1 * D_H + f);
        uint4 h2 = *(const uint4*)(H + (size_t)s2 * D_H + f);
        uint4 h3 = *(const uint4*)(H + (size_t)s3 * D_H + f);
        bf8_fma(h0, c0, acc);
        bf8_fma(h1, c1, acc);
        bf8_fma(h2, c2, acc);
        bf8_fma(h3, c3, acc);
    }
    for (; j < end; ++j) {
        int s0 = col[j];
        float c0 = dinv[s0] * dv;
        uint4 h0 = *(const uint4*)(H + (size_t)s0 * D_H + f);
        bf8_fma(h0, c0, acc);
    }
    uint4 hv = *(const uint4*)(H + (size_t)v * D_H + f);
    bf8_fma(hv, dv * dv, acc);  // self-loop
    float4 b0 = *(const float4*)(bias + f);
    float4 b1 = *(const float4*)(bias + f + 4);
    r[0] = fmaxf(acc[0] + b0.x, 0.f);
    r[1] = fmaxf(acc[1] + b0.y, 0.f);
    r[2] = fmaxf(acc[2] + b0.z, 0.f);
    r[3] = fmaxf(acc[3] + b0.w, 0.f);
    r[4] = fmaxf(acc[4] + b1.x, 0.f);
    r[5] = fmaxf(acc[5] + b1.y, 0.f);
    r[6] = fmaxf(acc[6] + b1.z, 0.f);
    r[7] = fmaxf(acc[7] + b1.w, 0.f);
}

// aggregation -> bf16 node features (used for both conv layers)
__global__ __launch_bounds__(64) void gather_agg_relu_bf16(const ushort_t* __restrict__ H,
                                                           const int* __restrict__ rowptr,
                                                           const int* __restrict__ col,
                                                           const float* __restrict__ dinv,
                                                           const float* __restrict__ bias,
                                                           ushort_t* __restrict__ out) {
    const int v = blockIdx.x;
    const int f = threadIdx.x * 8;
    float r[8];
    agg_node_bf16(H, rowptr, col, dinv, bias, v, f, r);
    ushort_t o[8];
#pragma unroll
    for (int i = 0; i < 8; ++i) o[i] = f2b(r[i]);
    *(uint4*)(out + (size_t)v * D_H + f) = *(uint4*)o;
}

// ---------------- segment max pool (batch is sorted; no atomics) ----------------
// gstart[g] = first node index with batch >= g, for g in [0, N_GRAPHS]
__global__ void graph_bounds(const int* __restrict__ batch, int* __restrict__ gstart) {
    int g = threadIdx.x;
    if (g > N_GRAPHS) return;
    int lo = 0, hi = N_NODES;
    while (lo < hi) {
        int mid = (lo + hi) >> 1;
        if (batch[mid] < g) lo = mid + 1; else hi = mid;
    }
    gstart[g] = lo;
}

// grid (N_GRAPHS, 4); block 64; thread covers 2 feats (one dword of bf16x2)
__global__ __launch_bounds__(64) void pool_max_seg(const ushort_t* __restrict__ h2,
                                                   const int* __restrict__ gstart,
                                                   float* __restrict__ gbuf) {
    const int g = blockIdx.x;
    const int f = blockIdx.y * 128 + threadIdx.x * 2;
    const int beg = gstart[g], end = gstart[g + 1];
    float m0 = -INFINITY, m1 = -INFINITY;
    int v = beg;
    for (; v + 3 < end; v += 4) {
        unsigned u0 = *(const unsigned*)(h2 + (size_t)(v + 0) * D_H + f);
        unsigned u1 = *(const unsigned*)(h2 + (size_t)(v + 1) * D_H + f);
        unsigned u2 = *(const unsigned*)(h2 + (size_t)(v + 2) * D_H + f);
        unsigned u3 = *(const unsigned*)(h2 + (size_t)(v + 3) * D_H + f);
        m0 = fmaxf(m0, fmaxf(fmaxf(__uint_as_float(u0 << 16), __uint_as_float(u1 << 16)),
                             fmaxf(__uint_as_float(u2 << 16), __uint_as_float(u3 << 16))));
        m1 = fmaxf(m1, fmaxf(fmaxf(__uint_as_float(u0 & 0xFFFF0000u), __uint_as_float(u1 & 0xFFFF0000u)),
                             fmaxf(__uint_as_float(u2 & 0xFFFF0000u), __uint_as_float(u3 & 0xFFFF0000u))));
    }
    for (; v < end; ++v) {
        unsigned u = *(const unsigned*)(h2 + (size_t)v * D_H + f);
        m0 = fmaxf(m0, __uint_as_float(u << 16));
        m1 = fmaxf(m1, __uint_as_float(u & 0xFFFF0000u));
    }
    gbuf[g * D_H + f] = m0;
    gbuf[g * D_H + f + 1] = m1;
}

__global__ void bias_relu(float* __restrict__ x, const float* __restrict__ b, int total, int N) {
    int i = blockIdx.x * blockDim.x + threadIdx.x;
    if (i < total) x[i] = fmaxf(x[i] + b[i % N], 0.f);
}

__global__ void bn_sigmoid(const float* __restrict__ logits, const float* __restrict__ b2,
                           const float* __restrict__ gamma, const float* __restrict__ beta,
                           float* __restrict__ out) {
    int i = blockIdx.x * blockDim.x + threadIdx.x;
    if (i >= N_GRAPHS * OUT_DIMS) return;
    int c = i % OUT_DIMS;
    const float s = 0.9999950000374997f;  // 1/sqrt(1+1e-5)
    float z = (logits[i] + b2[c]) * (gamma[c] * s) + beta[c];
    out[i] = 1.f / (1.f + expf(-z));
}

extern "C" void kernel_launch(void* const* d_in, const int* in_sizes, int n_in,
                              void* d_out, int out_size, void* d_ws, size_t ws_size,
                              hipStream_t stream) {
    const float* x     = (const float*)d_in[0];
    const int*   ei    = (const int*)d_in[1];    // int64 in reference -> int32 on device
    const int*   batch = (const int*)d_in[2];
    const float* Wg1   = (const float*)d_in[3];
    const float* bg1   = (const float*)d_in[4];
    const float* Wg2   = (const float*)d_in[5];
    const float* bg2   = (const float*)d_in[6];
    const float* W1    = (const float*)d_in[7];
    const float* b1    = (const float*)d_in[8];
    const float* W2    = (const float*)d_in[9];
    const float* b2    = (const float*)d_in[10];
    const float* gamma = (const float*)d_in[11];
    const float* beta  = (const float*)d_in[12];
    const int* src = ei;
    const int* dst = ei + N_EDGES;
    float* out = (float*)d_out;

    // workspace layout (all 16B-aligned)
    ushort_t* hpre   = (ushort_t*)d_ws;                        // [N_NODES, D_H] bf16 (conv GEMM out)
    ushort_t* h1b    = hpre + (size_t)N_NODES * D_H;           // [N_NODES, D_H] bf16 (h1; reused as h2)
    ushort_t* w1t    = h1b + (size_t)N_NODES * D_H;            // [D_H, D_IN] bf16 (Wg1^T)
    ushort_t* w2t    = w1t + (size_t)D_H * D_IN;               // [D_H, D_H] bf16 (Wg2^T)
    float*    dinv   = (float*)(w2t + (size_t)D_H * D_H);      // [N_NODES]
    float*    gbuf   = dinv + N_NODES;                         // [N_GRAPHS, D_H]
    float*    fc1o   = gbuf + N_GRAPHS * D_H;                  // [N_GRAPHS, D_FC]
    float*    logits = fc1o + N_GRAPHS * D_FC;                 // [N_GRAPHS, OUT_DIMS]
    int*      cnt    = (int*)(logits + N_GRAPHS * OUT_DIMS);   // [N_NODES]
    int*      rowptr = cnt + N_NODES;                          // [N_NODES+1]
    int*      cursor = rowptr + N_NODES + 1;                   // [N_NODES]
    int*      colidx = cursor + N_NODES;                       // [N_EDGES]
    int*      gstart = colidx + N_EDGES;                       // [N_GRAPHS+1]

    // ---- CSR build (by dst) + dinv + weight transpose/convert + graph bounds ----
    hipMemsetAsync(cnt, 0, N_NODES * sizeof(int), stream);
    hipMemsetAsync(cursor, 0, N_NODES * sizeof(int), stream);
    hist_deg<<<(N_EDGES + 255) / 256, 256, 0, stream>>>(dst, cnt);
    compute_dinv<<<(N_NODES + 255) / 256, 256, 0, stream>>>(cnt, dinv);
    scan_rowptr<<<1, 256, 0, stream>>>(cnt, rowptr);
    fill_csr<<<(N_EDGES + 255) / 256, 256, 0, stream>>>(src, dst, rowptr, cursor, colidx);
    wt_cvt_transpose<<<(D_H * D_IN + 255) / 256, 256, 0, stream>>>(Wg1, w1t, D_IN, D_H);
    wt_cvt_transpose<<<(D_H * D_H + 255) / 256, 256, 0, stream>>>(Wg2, w2t, D_H, D_H);
    graph_bounds<<<1, N_GRAPHS + 1, 0, stream>>>(batch, gstart);

    dim3 gconv((D_H + 127) / 128, (N_NODES + 127) / 128);  // (4, 157)

    // conv1: hpre = bf16(x @ Wg1) ; gather+relu -> h1b (bf16)
    mfma_gemm<true><<<gconv, 256, 0, stream>>>(x, w1t, hpre, N_NODES, D_H, D_IN);
    gather_agg_relu_bf16<<<N_NODES, 64, 0, stream>>>(hpre, rowptr, colidx, dinv, bg1, h1b);

    // conv2: hpre = bf16(h1b @ Wg2) ; gather+relu -> h2 (reuse h1b) ; segment pool
    mfma_gemm<false><<<gconv, 256, 0, stream>>>(h1b, w2t, hpre, N_NODES, D_H, D_H);
    gather_agg_relu_bf16<<<N_NODES, 64, 0, stream>>>(hpre, rowptr, colidx, dinv, bg2, h1b);
    pool_max_seg<<<dim3(N_GRAPHS, 4), 64, 0, stream>>>(h1b, gstart, gbuf);

    // fc1: [64,512]@[512,1024] + b1, relu
    dim3 gfc1((D_FC + 63) / 64, (N_GRAPHS + 63) / 64);
    gemm_tile<<<gfc1, 256, 0, stream>>>(gbuf, W1, fc1o, N_GRAPHS, D_FC, D_H);
    bias_relu<<<(N_GRAPHS * D_FC + 255) / 256, 256, 0, stream>>>(fc1o, b1, N_GRAPHS * D_FC, D_FC);

    // fc2: [64,1024]@[1024,5000] -> logits ; BN + sigmoid -> out
    dim3 gfc2((OUT_DIMS + 63) / 64, (N_GRAPHS + 63) / 64);
    gemm_tile<<<gfc2, 256, 0, stream>>>(fc1o, W2, logits, N_GRAPHS, OUT_DIMS, D_FC);
    bn_sigmoid<<<(N_GRAPHS * OUT_DIMS + 255) / 256, 256, 0, stream>>>(logits, b2, gamma, beta, out);
}

// Round 7
// 571.831 us; speedup vs baseline: 1.6576x; 1.2666x over previous
//
#include <hip/hip_runtime.h>
#include <math.h>

#define N_NODES 20000
#define N_EDGES 320000
#define N_GRAPHS 64
#define D_IN 1280
#define D_H 512
#define D_FC 1024
#define OUT_DIMS 5000

typedef unsigned short ushort_t;
typedef short bf16x8 __attribute__((ext_vector_type(8)));
typedef float f32x4 __attribute__((ext_vector_type(4)));

__device__ __forceinline__ ushort_t f2b(float x) {
    unsigned u = __float_as_uint(x);
    unsigned r = (u + 0x7FFFu + ((u >> 16) & 1u)) >> 16;  // RNE
    return (ushort_t)r;
}

// ============ bf16 MFMA GEMM: C[M,N] = A[M,K] @ BT[N,K]^T, C in bf16 ============
// 128x128 block tile, 4 waves, 64x64/wave as 4x4 grid of 16x16x32 MFMA.
// LDS tiles stored [dim][k], row stride 40 shorts (2-way bank aliasing = free).
// A_IS_F32: stage fp32 A with inline bf16 conversion; else A is bf16.
template <bool A_IS_F32>
__global__ __launch_bounds__(256) void mfma_gemm(const void* __restrict__ Ap,
                                                 const ushort_t* __restrict__ BT,
                                                 ushort_t* __restrict__ C,
                                                 int M, int N, int K) {
    __shared__ ushort_t As[128 * 40];
    __shared__ ushort_t Bs[128 * 40];
    const int t = threadIdx.x;
    const int lane = t & 63, wave = t >> 6;
    const int wrow = (wave >> 1) * 64, wcol = (wave & 1) * 64;
    const int lo = lane & 15, quad = lane >> 4;
    const int rowBase = blockIdx.y * 128;
    const int colBase = blockIdx.x * 128;

    f32x4 acc[4][4] = {};

    for (int k0 = 0; k0 < K; k0 += 32) {
        __syncthreads();
#pragma unroll
        for (int i = 0; i < 2; ++i) {  // stage A: 512 slots of 8 bf16
            int s = t + i * 256;
            int r = s >> 2, c8 = (s & 3) * 8;
            int gr = rowBase + r;
            ushort_t* dp = &As[r * 40 + c8];
            if (A_IS_F32) {
                const float* A = (const float*)Ap;
                float4 v0 = {0.f, 0.f, 0.f, 0.f}, v1 = {0.f, 0.f, 0.f, 0.f};
                if (gr < M) {
                    const float* p = A + (size_t)gr * K + k0 + c8;
                    v0 = *(const float4*)p;
                    v1 = *(const float4*)(p + 4);
                }
                ushort_t w[8] = {f2b(v0.x), f2b(v0.y), f2b(v0.z), f2b(v0.w),
                                 f2b(v1.x), f2b(v1.y), f2b(v1.z), f2b(v1.w)};
                *(uint4*)dp = *(uint4*)w;
            } else {
                const ushort_t* A = (const ushort_t*)Ap;
                uint4 v = {0u, 0u, 0u, 0u};
                if (gr < M) v = *(const uint4*)(A + (size_t)gr * K + k0 + c8);
                *(uint4*)dp = v;
            }
        }
#pragma unroll
        for (int i = 0; i < 2; ++i) {  // stage B (bf16, pre-transposed)
            int s = t + i * 256;
            int n = s >> 2, c8 = (s & 3) * 8;
            int gc = colBase + n;
            uint4 v = {0u, 0u, 0u, 0u};
            if (gc < N) v = *(const uint4*)(BT + (size_t)gc * K + k0 + c8);
            *(uint4*)&Bs[n * 40 + c8] = v;
        }
        __syncthreads();
        bf16x8 af[4], bfr[4];
#pragma unroll
        for (int i = 0; i < 4; ++i)
            af[i] = *(const bf16x8*)&As[(wrow + i * 16 + lo) * 40 + quad * 8];
#pragma unroll
        for (int j = 0; j < 4; ++j)
            bfr[j] = *(const bf16x8*)&Bs[(wcol + j * 16 + lo) * 40 + quad * 8];
#pragma unroll
        for (int i = 0; i < 4; ++i)
#pragma unroll
            for (int j = 0; j < 4; ++j)
                acc[i][j] = __builtin_amdgcn_mfma_f32_16x16x32_bf16(af[i], bfr[j], acc[i][j], 0, 0, 0);
    }
    // epilogue: C/D layout col=lane&15, row=quad*4+reg ; store bf16
#pragma unroll
    for (int i = 0; i < 4; ++i) {
        int row0 = rowBase + wrow + i * 16 + quad * 4;
#pragma unroll
        for (int j = 0; j < 4; ++j) {
            int col = colBase + wcol + j * 16 + lo;
            if (col >= N) continue;
#pragma unroll
            for (int r = 0; r < 4; ++r) {
                int row = row0 + r;
                if (row < M) C[(size_t)row * N + col] = f2b(acc[i][j][r]);
            }
        }
    }
}

// transpose + fp32->bf16: WT[n*K+k] = bf16(W[k*N+n])
__global__ void wt_cvt_transpose(const float* __restrict__ W, ushort_t* __restrict__ WT,
                                 int K, int N) {
    int i = blockIdx.x * blockDim.x + threadIdx.x;
    if (i >= N * K) return;
    int n = i / K, k = i - n * K;
    WT[i] = f2b(W[(size_t)k * N + n]);
}

// ---------------- fp32 split-K tiled GEMM (FC head) ----------------
// P[z][M][N] partial = A[M, kz..kz+KC] @ B[kz.., N] ; grid (Ntiles, Mtiles, S)
__global__ __launch_bounds__(256) void gemm_splitk(const float* __restrict__ A,
                                                   const float* __restrict__ B,
                                                   float* __restrict__ P,
                                                   int M, int N, int K, int KC) {
    __shared__ float As[16][64];
    __shared__ float Bs[16][64];
    const int t = threadIdx.x;
    const int tx = t & 15, ty = t >> 4;
    const int rowBase = blockIdx.y * 64;
    const int colBase = blockIdx.x * 64;
    const int kbeg = blockIdx.z * KC;
    const int kend = kbeg + KC;
    float acc[4][4] = {};
    for (int k0 = kbeg; k0 < kend; k0 += 16) {
#pragma unroll
        for (int i = 0; i < 4; ++i) {
            int idx = t + i * 256;
            int row = idx >> 4, kk = idx & 15;
            int gr = rowBase + row;
            As[kk][row] = (gr < M) ? A[(size_t)gr * K + k0 + kk] : 0.f;
        }
#pragma unroll
        for (int i = 0; i < 4; ++i) {
            int idx = t + i * 256;
            int kk = idx >> 6, col = idx & 63;
            int gc = colBase + col;
            Bs[kk][col] = (gc < N) ? B[(size_t)(k0 + kk) * N + gc] : 0.f;
        }
        __syncthreads();
#pragma unroll
        for (int kk = 0; kk < 16; ++kk) {
            float a[4], b[4];
#pragma unroll
            for (int i = 0; i < 4; ++i) a[i] = As[kk][ty * 4 + i];
#pragma unroll
            for (int j = 0; j < 4; ++j) b[j] = Bs[kk][tx * 4 + j];
#pragma unroll
            for (int i = 0; i < 4; ++i)
#pragma unroll
                for (int j = 0; j < 4; ++j) acc[i][j] = fmaf(a[i], b[j], acc[i][j]);
        }
        __syncthreads();
    }
    float* Pz = P + (size_t)blockIdx.z * M * N;
#pragma unroll
    for (int i = 0; i < 4; ++i) {
        int gr = rowBase + ty * 4 + i;
        if (gr >= M) continue;
#pragma unroll
        for (int j = 0; j < 4; ++j) {
            int gc = colBase + tx * 4 + j;
            if (gc < N) Pz[(size_t)gr * N + gc] = acc[i][j];
        }
    }
}

// fc1 reduce: out = relu(sum_z P[z] + b)
__global__ void reduce_bias_relu(const float* __restrict__ P, const float* __restrict__ b,
                                 float* __restrict__ out, int total, int N, int S) {
    int i = blockIdx.x * blockDim.x + threadIdx.x;
    if (i >= total) return;
    float s = 0.f;
    for (int z = 0; z < S; ++z) s += P[(size_t)z * total + i];
    out[i] = fmaxf(s + b[i % N], 0.f);
}

// fc2 reduce: out = sigmoid((sum_z P[z] + b2) * gamma/sqrt(1+eps) + beta)
__global__ void reduce_bn_sigmoid(const float* __restrict__ P, const float* __restrict__ b2,
                                  const float* __restrict__ gamma, const float* __restrict__ beta,
                                  float* __restrict__ out, int S) {
    int i = blockIdx.x * blockDim.x + threadIdx.x;
    if (i >= N_GRAPHS * OUT_DIMS) return;
    int c = i % OUT_DIMS;
    float s = 0.f;
    for (int z = 0; z < S; ++z) s += P[(size_t)z * N_GRAPHS * OUT_DIMS + i];
    const float sc = 0.9999950000374997f;  // 1/sqrt(1+1e-5)
    float zz = (s + b2[c]) * (gamma[c] * sc) + beta[c];
    out[i] = 1.f / (1.f + expf(-zz));
}

// ---------------- CSR construction ----------------
__global__ void hist_deg(const int* __restrict__ dst, int* __restrict__ cnt) {
    int e = blockIdx.x * blockDim.x + threadIdx.x;
    if (e < N_EDGES) atomicAdd(cnt + dst[e], 1);
}

__global__ void compute_dinv(const int* __restrict__ cnt, float* __restrict__ dinv) {
    int v = blockIdx.x * blockDim.x + threadIdx.x;
    if (v < N_NODES) dinv[v] = rsqrtf((float)cnt[v] + 1.0f);  // +1 self-loop
}

__global__ __launch_bounds__(256) void scan_rowptr(const int* __restrict__ cnt,
                                                   int* __restrict__ rowptr) {
    __shared__ int sums[256];
    const int t = threadIdx.x;
    const int CH = (N_NODES + 255) / 256;
    const int base = t * CH;
    int s = 0;
    for (int i = 0; i < CH; ++i) {
        int v = base + i;
        if (v < N_NODES) s += cnt[v];
    }
    sums[t] = s;
    __syncthreads();
    for (int off = 1; off < 256; off <<= 1) {
        int y = (t >= off) ? sums[t - off] : 0;
        __syncthreads();
        sums[t] += y;
        __syncthreads();
    }
    int run = sums[t] - s;
    for (int i = 0; i < CH; ++i) {
        int v = base + i;
        if (v < N_NODES) {
            rowptr[v] = run;
            run += cnt[v];
        }
    }
    if (t == 255) rowptr[N_NODES] = run;
}

__global__ void fill_csr(const int* __restrict__ src, const int* __restrict__ dst,
                         const int* __restrict__ rowptr, int* __restrict__ cursor,
                         int* __restrict__ col) {
    int e = blockIdx.x * blockDim.x + threadIdx.x;
    if (e < N_EDGES) {
        int d = dst[e];
        int p = rowptr[d] + atomicAdd(cursor + d, 1);
        col[p] = src[e];
    }
}

// ---------------- bf16 gather-aggregate ----------------
// one 64-thread wave per node; thread covers 8 feats (16 B); fp32 accum;
// 4-deep edge unroll for memory-level parallelism (latency-bound kernel)
__device__ __forceinline__ void bf8_fma(uint4 v, float c, float* acc) {
    unsigned a[4] = {v.x, v.y, v.z, v.w};
#pragma unroll
    for (int i = 0; i < 4; ++i) {
        float lo = __uint_as_float(a[i] << 16);
        float hi = __uint_as_float(a[i] & 0xFFFF0000u);
        acc[2 * i]     = fmaf(lo, c, acc[2 * i]);
        acc[2 * i + 1] = fmaf(hi, c, acc[2 * i + 1]);
    }
}

__device__ __forceinline__ void agg_node_bf16(const ushort_t* __restrict__ H,
                                              const int* __restrict__ rowptr,
                                              const int* __restrict__ col,
                                              const float* __restrict__ dinv,
                                              const float* __restrict__ bias,
                                              int v, int f, float* r) {
    const int beg = rowptr[v], end = rowptr[v + 1];
    const float dv = dinv[v];
    float acc[8] = {};
    int j = beg;
    for (; j + 3 < end; j += 4) {
        int s0 = col[j], s1 = col[j + 1], s2 = col[j + 2], s3 = col[j + 3];
        float c0 = dinv[s0] * dv, c1 = dinv[s1] * dv;
        float c2 = dinv[s2] * dv, c3 = dinv[s3] * dv;
        uint4 h0 = *(const uint4*)(H + (size_t)s0 * D_H + f);
        uint4 h1 = *(const uint4*)(H + (size_t)s1 * D_H + f);
        uint4 h2 = *(const uint4*)(H + (size_t)s2 * D_H + f);
        uint4 h3 = *(const uint4*)(H + (size_t)s3 * D_H + f);
        bf8_fma(h0, c0, acc);
        bf8_fma(h1, c1, acc);
        bf8_fma(h2, c2, acc);
        bf8_fma(h3, c3, acc);
    }
    for (; j < end; ++j) {
        int s0 = col[j];
        float c0 = dinv[s0] * dv;
        uint4 h0 = *(const uint4*)(H + (size_t)s0 * D_H + f);
        bf8_fma(h0, c0, acc);
    }
    uint4 hv = *(const uint4*)(H + (size_t)v * D_H + f);
    bf8_fma(hv, dv * dv, acc);  // self-loop
    float4 b0 = *(const float4*)(bias + f);
    float4 b1 = *(const float4*)(bias + f + 4);
    r[0] = fmaxf(acc[0] + b0.x, 0.f);
    r[1] = fmaxf(acc[1] + b0.y, 0.f);
    r[2] = fmaxf(acc[2] + b0.z, 0.f);
    r[3] = fmaxf(acc[3] + b0.w, 0.f);
    r[4] = fmaxf(acc[4] + b1.x, 0.f);
    r[5] = fmaxf(acc[5] + b1.y, 0.f);
    r[6] = fmaxf(acc[6] + b1.z, 0.f);
    r[7] = fmaxf(acc[7] + b1.w, 0.f);
}

// aggregation -> bf16 node features (used for both conv layers)
__global__ __launch_bounds__(64) void gather_agg_relu_bf16(const ushort_t* __restrict__ H,
                                                           const int* __restrict__ rowptr,
                                                           const int* __restrict__ col,
                                                           const float* __restrict__ dinv,
                                                           const float* __restrict__ bias,
                                                           ushort_t* __restrict__ out) {
    const int v = blockIdx.x;
    const int f = threadIdx.x * 8;
    float r[8];
    agg_node_bf16(H, rowptr, col, dinv, bias, v, f, r);
    ushort_t o[8];
#pragma unroll
    for (int i = 0; i < 8; ++i) o[i] = f2b(r[i]);
    *(uint4*)(out + (size_t)v * D_H + f) = *(uint4*)o;
}

// ---------------- segment max pool (batch is sorted; no atomics) ----------------
__global__ void graph_bounds(const int* __restrict__ batch, int* __restrict__ gstart) {
    int g = threadIdx.x;
    if (g > N_GRAPHS) return;
    int lo = 0, hi = N_NODES;
    while (lo < hi) {
        int mid = (lo + hi) >> 1;
        if (batch[mid] < g) lo = mid + 1; else hi = mid;
    }
    gstart[g] = lo;
}

// grid (N_GRAPHS, 4); block 64; thread covers 2 feats (one dword of bf16x2)
__global__ __launch_bounds__(64) void pool_max_seg(const ushort_t* __restrict__ h2,
                                                   const int* __restrict__ gstart,
                                                   float* __restrict__ gbuf) {
    const int g = blockIdx.x;
    const int f = blockIdx.y * 128 + threadIdx.x * 2;
    const int beg = gstart[g], end = gstart[g + 1];
    float m0 = -INFINITY, m1 = -INFINITY;
    int v = beg;
    for (; v + 3 < end; v += 4) {
        unsigned u0 = *(const unsigned*)(h2 + (size_t)(v + 0) * D_H + f);
        unsigned u1 = *(const unsigned*)(h2 + (size_t)(v + 1) * D_H + f);
        unsigned u2 = *(const unsigned*)(h2 + (size_t)(v + 2) * D_H + f);
        unsigned u3 = *(const unsigned*)(h2 + (size_t)(v + 3) * D_H + f);
        m0 = fmaxf(m0, fmaxf(fmaxf(__uint_as_float(u0 << 16), __uint_as_float(u1 << 16)),
                             fmaxf(__uint_as_float(u2 << 16), __uint_as_float(u3 << 16))));
        m1 = fmaxf(m1, fmaxf(fmaxf(__uint_as_float(u0 & 0xFFFF0000u), __uint_as_float(u1 & 0xFFFF0000u)),
                             fmaxf(__uint_as_float(u2 & 0xFFFF0000u), __uint_as_float(u3 & 0xFFFF0000u))));
    }
    for (; v < end; ++v) {
        unsigned u = *(const unsigned*)(h2 + (size_t)v * D_H + f);
        m0 = fmaxf(m0, __uint_as_float(u << 16));
        m1 = fmaxf(m1, __uint_as_float(u & 0xFFFF0000u));
    }
    gbuf[g * D_H + f] = m0;
    gbuf[g * D_H + f + 1] = m1;
}

extern "C" void kernel_launch(void* const* d_in, const int* in_sizes, int n_in,
                              void* d_out, int out_size, void* d_ws, size_t ws_size,
                              hipStream_t stream) {
    const float* x     = (const float*)d_in[0];
    const int*   ei    = (const int*)d_in[1];    // int64 in reference -> int32 on device
    const int*   batch = (const int*)d_in[2];
    const float* Wg1   = (const float*)d_in[3];
    const float* bg1   = (const float*)d_in[4];
    const float* Wg2   = (const float*)d_in[5];
    const float* bg2   = (const float*)d_in[6];
    const float* W1    = (const float*)d_in[7];
    const float* b1    = (const float*)d_in[8];
    const float* W2    = (const float*)d_in[9];
    const float* b2    = (const float*)d_in[10];
    const float* gamma = (const float*)d_in[11];
    const float* beta  = (const float*)d_in[12];
    const int* src = ei;
    const int* dst = ei + N_EDGES;
    float* out = (float*)d_out;

    const int S1 = 4;  // fc1 K-split (K=512, KC=128)
    const int S2 = 8;  // fc2 K-split (K=1024, KC=128)

    // workspace layout (all 16B-aligned)
    ushort_t* hpre   = (ushort_t*)d_ws;                        // [N_NODES, D_H] bf16 (conv GEMM out)
    ushort_t* h1b    = hpre + (size_t)N_NODES * D_H;           // [N_NODES, D_H] bf16 (h1; reused as h2)
    ushort_t* w1t    = h1b + (size_t)N_NODES * D_H;            // [D_H, D_IN] bf16 (Wg1^T)
    ushort_t* w2t    = w1t + (size_t)D_H * D_IN;               // [D_H, D_H] bf16 (Wg2^T)
    float*    dinv   = (float*)(w2t + (size_t)D_H * D_H);      // [N_NODES]
    float*    gbuf   = dinv + N_NODES;                         // [N_GRAPHS, D_H]
    float*    fc1o   = gbuf + N_GRAPHS * D_H;                  // [N_GRAPHS, D_FC]
    float*    part1  = fc1o + N_GRAPHS * D_FC;                 // [S1, 64, D_FC]
    float*    part2  = part1 + (size_t)S1 * N_GRAPHS * D_FC;   // [S2, 64, OUT_DIMS]
    int*      cnt    = (int*)(part2 + (size_t)S2 * N_GRAPHS * OUT_DIMS);  // [N_NODES]
    int*      rowptr = cnt + N_NODES;                          // [N_NODES+1]
    int*      cursor = rowptr + N_NODES + 1;                   // [N_NODES]
    int*      colidx = cursor + N_NODES;                       // [N_EDGES]
    int*      gstart = colidx + N_EDGES;                       // [N_GRAPHS+1]

    // ---- CSR build (by dst) + dinv + weight transpose/convert + graph bounds ----
    hipMemsetAsync(cnt, 0, N_NODES * sizeof(int), stream);
    hipMemsetAsync(cursor, 0, N_NODES * sizeof(int), stream);
    hist_deg<<<(N_EDGES + 255) / 256, 256, 0, stream>>>(dst, cnt);
    compute_dinv<<<(N_NODES + 255) / 256, 256, 0, stream>>>(cnt, dinv);
    scan_rowptr<<<1, 256, 0, stream>>>(cnt, rowptr);
    fill_csr<<<(N_EDGES + 255) / 256, 256, 0, stream>>>(src, dst, rowptr, cursor, colidx);
    wt_cvt_transpose<<<(D_H * D_IN + 255) / 256, 256, 0, stream>>>(Wg1, w1t, D_IN, D_H);
    wt_cvt_transpose<<<(D_H * D_H + 255) / 256, 256, 0, stream>>>(Wg2, w2t, D_H, D_H);
    graph_bounds<<<1, N_GRAPHS + 1, 0, stream>>>(batch, gstart);

    dim3 gconv((D_H + 127) / 128, (N_NODES + 127) / 128);  // (4, 157)

    // conv1: hpre = bf16(x @ Wg1) ; gather+relu -> h1b (bf16)
    mfma_gemm<true><<<gconv, 256, 0, stream>>>(x, w1t, hpre, N_NODES, D_H, D_IN);
    gather_agg_relu_bf16<<<N_NODES, 64, 0, stream>>>(hpre, rowptr, colidx, dinv, bg1, h1b);

    // conv2: hpre = bf16(h1b @ Wg2) ; gather+relu -> h2 (reuse h1b) ; segment pool
    mfma_gemm<false><<<gconv, 256, 0, stream>>>(h1b, w2t, hpre, N_NODES, D_H, D_H);
    gather_agg_relu_bf16<<<N_NODES, 64, 0, stream>>>(hpre, rowptr, colidx, dinv, bg2, h1b);
    pool_max_seg<<<dim3(N_GRAPHS, 4), 64, 0, stream>>>(h1b, gstart, gbuf);

    // fc1: [64,512]@[512,1024] split-K=4 -> part1 ; reduce + b1 + relu -> fc1o
    dim3 gfc1((D_FC + 63) / 64, 1, S1);
    gemm_splitk<<<gfc1, 256, 0, stream>>>(gbuf, W1, part1, N_GRAPHS, D_FC, D_H, D_H / S1);
    reduce_bias_relu<<<(N_GRAPHS * D_FC + 255) / 256, 256, 0, stream>>>(
        part1, b1, fc1o, N_GRAPHS * D_FC, D_FC, S1);

    // fc2: [64,1024]@[1024,5000] split-K=8 -> part2 ; reduce + BN + sigmoid -> out
    dim3 gfc2((OUT_DIMS + 63) / 64, 1, S2);
    gemm_splitk<<<gfc2, 256, 0, stream>>>(fc1o, W2, part2, N_GRAPHS, OUT_DIMS, D_FC, D_FC / S2);
    reduce_bn_sigmoid<<<(N_GRAPHS * OUT_DIMS + 255) / 256, 256, 0, stream>>>(
        part2, b2, gamma, beta, out, S2);
}

// Round 8
// 539.293 us; speedup vs baseline: 1.7576x; 1.0603x over previous
//
#include <hip/hip_runtime.h>
#include <math.h>

#define N_NODES 20000
#define N_EDGES 320000
#define N_GRAPHS 64
#define D_IN 1280
#define D_H 512
#define D_FC 1024
#define OUT_DIMS 5000

typedef unsigned short ushort_t;
typedef short bf16x8 __attribute__((ext_vector_type(8)));
typedef float f32x4 __attribute__((ext_vector_type(4)));

__device__ __forceinline__ ushort_t f2b(float x) {
    unsigned u = __float_as_uint(x);
    unsigned r = (u + 0x7FFFu + ((u >> 16) & 1u)) >> 16;  // RNE
    return (ushort_t)r;
}

// async 16B global->LDS DMA: per-lane gptr, wave-uniform LDS base + lane*16
#define GLL16(gp, lp)                                                                  \
    __builtin_amdgcn_global_load_lds((const __attribute__((address_space(1))) void*)(gp), \
                                     (__attribute__((address_space(3))) void*)(lp), 16, 0, 0)

// XCD swizzle for conv GEMMs: grid (32, 20) -> f in [0,640)
// rt = (f>>5)*8 + (f&7), ct = (f&31)>>3 ; 4 col-tiles of a row-tile share f%8 (same XCD)
#define CONV_SWIZZLE()                                         \
    const int f = blockIdx.y * 32 + blockIdx.x;                \
    const int rt = (f >> 5) * 8 + (f & 7);                     \
    const int ct = (f & 31) >> 3;                              \
    const int rowBase = rt * 128;                              \
    const int colBase = ct * 128;                              \
    if (rowBase >= M) return;

// ============ conv2-style GEMM: A bf16, both tiles via global_load_lds ============
// 128x128 tile, 4 waves (64x64 each, 4x4 of 16x16x32 MFMA), BK=32, unpadded LDS [128][32].
__global__ __launch_bounds__(256) void mfma_gemm_async(const ushort_t* __restrict__ A,
                                                       const ushort_t* __restrict__ BT,
                                                       ushort_t* __restrict__ C,
                                                       int M, int N, int K) {
    __shared__ ushort_t As[128 * 32];
    __shared__ ushort_t Bs[128 * 32];
    const int t = threadIdx.x;
    const int lane = t & 63, wave = t >> 6;
    const int wrow = (wave >> 1) * 64, wcol = (wave & 1) * 64;
    const int lo = lane & 15, quad = lane >> 4;
    CONV_SWIZZLE();

    // staging slots: s = i*256 + t ; row = s>>2 ; 8 bf16 chunk c8 = (s&3)*8
    const int s0 = t, s1 = t + 256;
    int ar0 = rowBase + (s0 >> 2); if (ar0 >= M) ar0 = M - 1;  // clamp: garbage rows never stored
    int ar1 = rowBase + (s1 >> 2); if (ar1 >= M) ar1 = M - 1;
    const ushort_t* pa0 = A + (size_t)ar0 * K + (s0 & 3) * 8;
    const ushort_t* pa1 = A + (size_t)ar1 * K + (s1 & 3) * 8;
    const ushort_t* pb0 = BT + (size_t)(colBase + (s0 >> 2)) * K + (s0 & 3) * 8;
    const ushort_t* pb1 = BT + (size_t)(colBase + (s1 >> 2)) * K + (s1 & 3) * 8;
    // wave-uniform LDS bases (1024 B per wave per call)
    ushort_t* lA0 = As + wave * 512;
    ushort_t* lA1 = As + 2048 + wave * 512;
    ushort_t* lB0 = Bs + wave * 512;
    ushort_t* lB1 = Bs + 2048 + wave * 512;

    f32x4 acc[4][4] = {};

    for (int kk = 0; kk < K; kk += 32) {
        __syncthreads();  // prev tile reads complete
        GLL16(pa0, lA0);
        GLL16(pa1, lA1);
        GLL16(pb0, lB0);
        GLL16(pb1, lB1);
        pa0 += 32; pa1 += 32; pb0 += 32; pb1 += 32;
        __syncthreads();  // drains vmcnt -> tile visible
        bf16x8 af[4], bfr[4];
#pragma unroll
        for (int i = 0; i < 4; ++i)
            af[i] = *(const bf16x8*)&As[(wrow + i * 16 + lo) * 32 + quad * 8];
#pragma unroll
        for (int j = 0; j < 4; ++j)
            bfr[j] = *(const bf16x8*)&Bs[(wcol + j * 16 + lo) * 32 + quad * 8];
#pragma unroll
        for (int i = 0; i < 4; ++i)
#pragma unroll
            for (int j = 0; j < 4; ++j)
                acc[i][j] = __builtin_amdgcn_mfma_f32_16x16x32_bf16(af[i], bfr[j], acc[i][j], 0, 0, 0);
    }
    // epilogue: C/D layout col=lane&15, row=quad*4+reg ; store bf16
#pragma unroll
    for (int i = 0; i < 4; ++i) {
        int row0 = rowBase + wrow + i * 16 + quad * 4;
#pragma unroll
        for (int j = 0; j < 4; ++j) {
            int col = colBase + wcol + j * 16 + lo;
            if (col >= N) continue;
#pragma unroll
            for (int r = 0; r < 4; ++r) {
                int row = row0 + r;
                if (row < M) C[(size_t)row * N + col] = f2b(acc[i][j][r]);
            }
        }
    }
}

// ============ conv1 GEMM: A fp32 (staged via VGPR + cvt), B via global_load_lds ============
__global__ __launch_bounds__(256) void mfma_gemm_f32a(const float* __restrict__ A,
                                                      const ushort_t* __restrict__ BT,
                                                      ushort_t* __restrict__ C,
                                                      int M, int N, int K) {
    __shared__ ushort_t As[128 * 32];
    __shared__ ushort_t Bs[128 * 32];
    const int t = threadIdx.x;
    const int lane = t & 63, wave = t >> 6;
    const int wrow = (wave >> 1) * 64, wcol = (wave & 1) * 64;
    const int lo = lane & 15, quad = lane >> 4;
    CONV_SWIZZLE();

    const int s0 = t, s1 = t + 256;
    int ar0 = rowBase + (s0 >> 2); if (ar0 >= M) ar0 = M - 1;
    int ar1 = rowBase + (s1 >> 2); if (ar1 >= M) ar1 = M - 1;
    const float* pa0 = A + (size_t)ar0 * K + (s0 & 3) * 8;
    const float* pa1 = A + (size_t)ar1 * K + (s1 & 3) * 8;
    const ushort_t* pb0 = BT + (size_t)(colBase + (s0 >> 2)) * K + (s0 & 3) * 8;
    const ushort_t* pb1 = BT + (size_t)(colBase + (s1 >> 2)) * K + (s1 & 3) * 8;
    ushort_t* lB0 = Bs + wave * 512;
    ushort_t* lB1 = Bs + 2048 + wave * 512;
    ushort_t* dA0 = &As[(size_t)s0 * 8];
    ushort_t* dA1 = &As[(size_t)s1 * 8];

    f32x4 acc[4][4] = {};

    for (int kk = 0; kk < K; kk += 32) {
        __syncthreads();
        GLL16(pb0, lB0);
        GLL16(pb1, lB1);
        float4 v00 = *(const float4*)pa0;
        float4 v01 = *(const float4*)(pa0 + 4);
        float4 v10 = *(const float4*)pa1;
        float4 v11 = *(const float4*)(pa1 + 4);
        pa0 += 32; pa1 += 32; pb0 += 32; pb1 += 32;
        ushort_t w0[8] = {f2b(v00.x), f2b(v00.y), f2b(v00.z), f2b(v00.w),
                          f2b(v01.x), f2b(v01.y), f2b(v01.z), f2b(v01.w)};
        ushort_t w1[8] = {f2b(v10.x), f2b(v10.y), f2b(v10.z), f2b(v10.w),
                          f2b(v11.x), f2b(v11.y), f2b(v11.z), f2b(v11.w)};
        *(uint4*)dA0 = *(uint4*)w0;
        *(uint4*)dA1 = *(uint4*)w1;
        __syncthreads();
        bf16x8 af[4], bfr[4];
#pragma unroll
        for (int i = 0; i < 4; ++i)
            af[i] = *(const bf16x8*)&As[(wrow + i * 16 + lo) * 32 + quad * 8];
#pragma unroll
        for (int j = 0; j < 4; ++j)
            bfr[j] = *(const bf16x8*)&Bs[(wcol + j * 16 + lo) * 32 + quad * 8];
#pragma unroll
        for (int i = 0; i < 4; ++i)
#pragma unroll
            for (int j = 0; j < 4; ++j)
                acc[i][j] = __builtin_amdgcn_mfma_f32_16x16x32_bf16(af[i], bfr[j], acc[i][j], 0, 0, 0);
    }
#pragma unroll
    for (int i = 0; i < 4; ++i) {
        int row0 = rowBase + wrow + i * 16 + quad * 4;
#pragma unroll
        for (int j = 0; j < 4; ++j) {
            int col = colBase + wcol + j * 16 + lo;
            if (col >= N) continue;
#pragma unroll
            for (int r = 0; r < 4; ++r) {
                int row = row0 + r;
                if (row < M) C[(size_t)row * N + col] = f2b(acc[i][j][r]);
            }
        }
    }
}

// transpose + fp32->bf16: WT[n*K+k] = bf16(W[k*N+n])
__global__ void wt_cvt_transpose(const float* __restrict__ W, ushort_t* __restrict__ WT,
                                 int K, int N) {
    int i = blockIdx.x * blockDim.x + threadIdx.x;
    if (i >= N * K) return;
    int n = i / K, k = i - n * K;
    WT[i] = f2b(W[(size_t)k * N + n]);
}

// ---------------- fp32 split-K tiled GEMM (FC head) ----------------
__global__ __launch_bounds__(256) void gemm_splitk(const float* __restrict__ A,
                                                   const float* __restrict__ B,
                                                   float* __restrict__ P,
                                                   int M, int N, int K, int KC) {
    __shared__ float As[16][64];
    __shared__ float Bs[16][64];
    const int t = threadIdx.x;
    const int tx = t & 15, ty = t >> 4;
    const int rowBase = blockIdx.y * 64;
    const int colBase = blockIdx.x * 64;
    const int kbeg = blockIdx.z * KC;
    const int kend = kbeg + KC;
    float acc[4][4] = {};
    for (int k0 = kbeg; k0 < kend; k0 += 16) {
#pragma unroll
        for (int i = 0; i < 4; ++i) {
            int idx = t + i * 256;
            int row = idx >> 4, kk = idx & 15;
            int gr = rowBase + row;
            As[kk][row] = (gr < M) ? A[(size_t)gr * K + k0 + kk] : 0.f;
        }
#pragma unroll
        for (int i = 0; i < 4; ++i) {
            int idx = t + i * 256;
            int kk = idx >> 6, col = idx & 63;
            int gc = colBase + col;
            Bs[kk][col] = (gc < N) ? B[(size_t)(k0 + kk) * N + gc] : 0.f;
        }
        __syncthreads();
#pragma unroll
        for (int kk = 0; kk < 16; ++kk) {
            float a[4], b[4];
#pragma unroll
            for (int i = 0; i < 4; ++i) a[i] = As[kk][ty * 4 + i];
#pragma unroll
            for (int j = 0; j < 4; ++j) b[j] = Bs[kk][tx * 4 + j];
#pragma unroll
            for (int i = 0; i < 4; ++i)
#pragma unroll
                for (int j = 0; j < 4; ++j) acc[i][j] = fmaf(a[i], b[j], acc[i][j]);
        }
        __syncthreads();
    }
    float* Pz = P + (size_t)blockIdx.z * M * N;
#pragma unroll
    for (int i = 0; i < 4; ++i) {
        int gr = rowBase + ty * 4 + i;
        if (gr >= M) continue;
#pragma unroll
        for (int j = 0; j < 4; ++j) {
            int gc = colBase + tx * 4 + j;
            if (gc < N) Pz[(size_t)gr * N + gc] = acc[i][j];
        }
    }
}

// fc1 reduce: out = relu(sum_z P[z] + b)
__global__ void reduce_bias_relu(const float* __restrict__ P, const float* __restrict__ b,
                                 float* __restrict__ out, int total, int N, int S) {
    int i = blockIdx.x * blockDim.x + threadIdx.x;
    if (i >= total) return;
    float s = 0.f;
    for (int z = 0; z < S; ++z) s += P[(size_t)z * total + i];
    out[i] = fmaxf(s + b[i % N], 0.f);
}

// fc2 reduce: out = sigmoid((sum_z P[z] + b2) * gamma/sqrt(1+eps) + beta)
__global__ void reduce_bn_sigmoid(const float* __restrict__ P, const float* __restrict__ b2,
                                  const float* __restrict__ gamma, const float* __restrict__ beta,
                                  float* __restrict__ out, int S) {
    int i = blockIdx.x * blockDim.x + threadIdx.x;
    if (i >= N_GRAPHS * OUT_DIMS) return;
    int c = i % OUT_DIMS;
    float s = 0.f;
    for (int z = 0; z < S; ++z) s += P[(size_t)z * N_GRAPHS * OUT_DIMS + i];
    const float sc = 0.9999950000374997f;  // 1/sqrt(1+1e-5)
    float zz = (s + b2[c]) * (gamma[c] * sc) + beta[c];
    out[i] = 1.f / (1.f + expf(-zz));
}

// ---------------- CSR construction ----------------
__global__ void hist_deg(const int* __restrict__ dst, int* __restrict__ cnt) {
    int e = blockIdx.x * blockDim.x + threadIdx.x;
    if (e < N_EDGES) atomicAdd(cnt + dst[e], 1);
}

__global__ void compute_dinv(const int* __restrict__ cnt, float* __restrict__ dinv) {
    int v = blockIdx.x * blockDim.x + threadIdx.x;
    if (v < N_NODES) dinv[v] = rsqrtf((float)cnt[v] + 1.0f);  // +1 self-loop
}

__global__ __launch_bounds__(256) void scan_rowptr(const int* __restrict__ cnt,
                                                   int* __restrict__ rowptr) {
    __shared__ int sums[256];
    const int t = threadIdx.x;
    const int CH = (N_NODES + 255) / 256;
    const int base = t * CH;
    int s = 0;
    for (int i = 0; i < CH; ++i) {
        int v = base + i;
        if (v < N_NODES) s += cnt[v];
    }
    sums[t] = s;
    __syncthreads();
    for (int off = 1; off < 256; off <<= 1) {
        int y = (t >= off) ? sums[t - off] : 0;
        __syncthreads();
        sums[t] += y;
        __syncthreads();
    }
    int run = sums[t] - s;
    for (int i = 0; i < CH; ++i) {
        int v = base + i;
        if (v < N_NODES) {
            rowptr[v] = run;
            run += cnt[v];
        }
    }
    if (t == 255) rowptr[N_NODES] = run;
}

__global__ void fill_csr(const int* __restrict__ src, const int* __restrict__ dst,
                         const int* __restrict__ rowptr, int* __restrict__ cursor,
                         int* __restrict__ col) {
    int e = blockIdx.x * blockDim.x + threadIdx.x;
    if (e < N_EDGES) {
        int d = dst[e];
        int p = rowptr[d] + atomicAdd(cursor + d, 1);
        col[p] = src[e];
    }
}

// ---------------- bf16 gather-aggregate ----------------
__device__ __forceinline__ void bf8_fma(uint4 v, float c, float* acc) {
    unsigned a[4] = {v.x, v.y, v.z, v.w};
#pragma unroll
    for (int i = 0; i < 4; ++i) {
        float lo = __uint_as_float(a[i] << 16);
        float hi = __uint_as_float(a[i] & 0xFFFF0000u);
        acc[2 * i]     = fmaf(lo, c, acc[2 * i]);
        acc[2 * i + 1] = fmaf(hi, c, acc[2 * i + 1]);
    }
}

__device__ __forceinline__ void agg_node_bf16(const ushort_t* __restrict__ H,
                                              const int* __restrict__ rowptr,
                                              const int* __restrict__ col,
                                              const float* __restrict__ dinv,
                                              const float* __restrict__ bias,
                                              int v, int f, float* r) {
    const int beg = rowptr[v], end = rowptr[v + 1];
    const float dv = dinv[v];
    float acc[8] = {};
    int j = beg;
    for (; j + 3 < end; j += 4) {
        int s0 = col[j], s1 = col[j + 1], s2 = col[j + 2], s3 = col[j + 3];
        float c0 = dinv[s0] * dv, c1 = dinv[s1] * dv;
        float c2 = dinv[s2] * dv, c3 = dinv[s3] * dv;
        uint4 h0 = *(const uint4*)(H + (size_t)s0 * D_H + f);
        uint4 h1 = *(const uint4*)(H + (size_t)s1 * D_H + f);
        uint4 h2 = *(const uint4*)(H + (size_t)s2 * D_H + f);
        uint4 h3 = *(const uint4*)(H + (size_t)s3 * D_H + f);
        bf8_fma(h0, c0, acc);
        bf8_fma(h1, c1, acc);
        bf8_fma(h2, c2, acc);
        bf8_fma(h3, c3, acc);
    }
    for (; j < end; ++j) {
        int s0 = col[j];
        float c0 = dinv[s0] * dv;
        uint4 h0 = *(const uint4*)(H + (size_t)s0 * D_H + f);
        bf8_fma(h0, c0, acc);
    }
    uint4 hv = *(const uint4*)(H + (size_t)v * D_H + f);
    bf8_fma(hv, dv * dv, acc);  // self-loop
    float4 b0 = *(const float4*)(bias + f);
    float4 b1 = *(const float4*)(bias + f + 4);
    r[0] = fmaxf(acc[0] + b0.x, 0.f);
    r[1] = fmaxf(acc[1] + b0.y, 0.f);
    r[2] = fmaxf(acc[2] + b0.z, 0.f);
    r[3] = fmaxf(acc[3] + b0.w, 0.f);
    r[4] = fmaxf(acc[4] + b1.x, 0.f);
    r[5] = fmaxf(acc[5] + b1.y, 0.f);
    r[6] = fmaxf(acc[6] + b1.z, 0.f);
    r[7] = fmaxf(acc[7] + b1.w, 0.f);
}

__global__ __launch_bounds__(64) void gather_agg_relu_bf16(const ushort_t* __restrict__ H,
                                                           const int* __restrict__ rowptr,
                                                           const int* __restrict__ col,
                                                           const float* __restrict__ dinv,
                                                           const float* __restrict__ bias,
                                                           ushort_t* __restrict__ out) {
    const int v = blockIdx.x;
    const int f = threadIdx.x * 8;
    float r[8];
    agg_node_bf16(H, rowptr, col, dinv, bias, v, f, r);
    ushort_t o[8];
#pragma unroll
    for (int i = 0; i < 8; ++i) o[i] = f2b(r[i]);
    *(uint4*)(out + (size_t)v * D_H + f) = *(uint4*)o;
}

// ---------------- segment max pool (batch is sorted; no atomics) ----------------
__global__ void graph_bounds(const int* __restrict__ batch, int* __restrict__ gstart) {
    int g = threadIdx.x;
    if (g > N_GRAPHS) return;
    int lo = 0, hi = N_NODES;
    while (lo < hi) {
        int mid = (lo + hi) >> 1;
        if (batch[mid] < g) lo = mid + 1; else hi = mid;
    }
    gstart[g] = lo;
}

__global__ __launch_bounds__(64) void pool_max_seg(const ushort_t* __restrict__ h2,
                                                   const int* __restrict__ gstart,
                                                   float* __restrict__ gbuf) {
    const int g = blockIdx.x;
    const int f = blockIdx.y * 128 + threadIdx.x * 2;
    const int beg = gstart[g], end = gstart[g + 1];
    float m0 = -INFINITY, m1 = -INFINITY;
    int v = beg;
    for (; v + 3 < end; v += 4) {
        unsigned u0 = *(const unsigned*)(h2 + (size_t)(v + 0) * D_H + f);
        unsigned u1 = *(const unsigned*)(h2 + (size_t)(v + 1) * D_H + f);
        unsigned u2 = *(const unsigned*)(h2 + (size_t)(v + 2) * D_H + f);
        unsigned u3 = *(const unsigned*)(h2 + (size_t)(v + 3) * D_H + f);
        m0 = fmaxf(m0, fmaxf(fmaxf(__uint_as_float(u0 << 16), __uint_as_float(u1 << 16)),
                             fmaxf(__uint_as_float(u2 << 16), __uint_as_float(u3 << 16))));
        m1 = fmaxf(m1, fmaxf(fmaxf(__uint_as_float(u0 & 0xFFFF0000u), __uint_as_float(u1 & 0xFFFF0000u)),
                             fmaxf(__uint_as_float(u2 & 0xFFFF0000u), __uint_as_float(u3 & 0xFFFF0000u))));
    }
    for (; v < end; ++v) {
        unsigned u = *(const unsigned*)(h2 + (size_t)v * D_H + f);
        m0 = fmaxf(m0, __uint_as_float(u << 16));
        m1 = fmaxf(m1, __uint_as_float(u & 0xFFFF0000u));
    }
    gbuf[g * D_H + f] = m0;
    gbuf[g * D_H + f + 1] = m1;
}

extern "C" void kernel_launch(void* const* d_in, const int* in_sizes, int n_in,
                              void* d_out, int out_size, void* d_ws, size_t ws_size,
                              hipStream_t stream) {
    const float* x     = (const float*)d_in[0];
    const int*   ei    = (const int*)d_in[1];    // int64 in reference -> int32 on device
    const int*   batch = (const int*)d_in[2];
    const float* Wg1   = (const float*)d_in[3];
    const float* bg1   = (const float*)d_in[4];
    const float* Wg2   = (const float*)d_in[5];
    const float* bg2   = (const float*)d_in[6];
    const float* W1    = (const float*)d_in[7];
    const float* b1    = (const float*)d_in[8];
    const float* W2    = (const float*)d_in[9];
    const float* b2    = (const float*)d_in[10];
    const float* gamma = (const float*)d_in[11];
    const float* beta  = (const float*)d_in[12];
    const int* src = ei;
    const int* dst = ei + N_EDGES;
    float* out = (float*)d_out;

    const int S1 = 4;  // fc1 K-split (K=512, KC=128)
    const int S2 = 8;  // fc2 K-split (K=1024, KC=128)

    // workspace layout (all 16B-aligned)
    ushort_t* hpre   = (ushort_t*)d_ws;                        // [N_NODES, D_H] bf16 (conv GEMM out)
    ushort_t* h1b    = hpre + (size_t)N_NODES * D_H;           // [N_NODES, D_H] bf16 (h1; reused as h2)
    ushort_t* w1t    = h1b + (size_t)N_NODES * D_H;            // [D_H, D_IN] bf16 (Wg1^T)
    ushort_t* w2t    = w1t + (size_t)D_H * D_IN;               // [D_H, D_H] bf16 (Wg2^T)
    float*    dinv   = (float*)(w2t + (size_t)D_H * D_H);      // [N_NODES]
    float*    gbuf   = dinv + N_NODES;                         // [N_GRAPHS, D_H]
    float*    fc1o   = gbuf + N_GRAPHS * D_H;                  // [N_GRAPHS, D_FC]
    float*    part1  = fc1o + N_GRAPHS * D_FC;                 // [S1, 64, D_FC]
    float*    part2  = part1 + (size_t)S1 * N_GRAPHS * D_FC;   // [S2, 64, OUT_DIMS]
    int*      cnt    = (int*)(part2 + (size_t)S2 * N_GRAPHS * OUT_DIMS);  // [N_NODES]
    int*      rowptr = cnt + N_NODES;                          // [N_NODES+1]
    int*      cursor = rowptr + N_NODES + 1;                   // [N_NODES]
    int*      colidx = cursor + N_NODES;                       // [N_EDGES]
    int*      gstart = colidx + N_EDGES;                       // [N_GRAPHS+1]

    // ---- CSR build (by dst) + dinv + weight transpose/convert + graph bounds ----
    hipMemsetAsync(cnt, 0, N_NODES * sizeof(int), stream);
    hipMemsetAsync(cursor, 0, N_NODES * sizeof(int), stream);
    hist_deg<<<(N_EDGES + 255) / 256, 256, 0, stream>>>(dst, cnt);
    compute_dinv<<<(N_NODES + 255) / 256, 256, 0, stream>>>(cnt, dinv);
    scan_rowptr<<<1, 256, 0, stream>>>(cnt, rowptr);
    fill_csr<<<(N_EDGES + 255) / 256, 256, 0, stream>>>(src, dst, rowptr, cursor, colidx);
    wt_cvt_transpose<<<(D_H * D_IN + 255) / 256, 256, 0, stream>>>(Wg1, w1t, D_IN, D_H);
    wt_cvt_transpose<<<(D_H * D_H + 255) / 256, 256, 0, stream>>>(Wg2, w2t, D_H, D_H);
    graph_bounds<<<1, N_GRAPHS + 1, 0, stream>>>(batch, gstart);

    dim3 gconv(32, 20);  // swizzled: 640 slots, 628 active (157 row-tiles x 4 col-tiles)

    // conv1: hpre = bf16(x @ Wg1) ; gather+relu -> h1b (bf16)
    mfma_gemm_f32a<<<gconv, 256, 0, stream>>>(x, w1t, hpre, N_NODES, D_H, D_IN);
    gather_agg_relu_bf16<<<N_NODES, 64, 0, stream>>>(hpre, rowptr, colidx, dinv, bg1, h1b);

    // conv2: hpre = bf16(h1b @ Wg2) ; gather+relu -> h2 (reuse h1b) ; segment pool
    mfma_gemm_async<<<gconv, 256, 0, stream>>>(h1b, w2t, hpre, N_NODES, D_H, D_H);
    gather_agg_relu_bf16<<<N_NODES, 64, 0, stream>>>(hpre, rowptr, colidx, dinv, bg2, h1b);
    pool_max_seg<<<dim3(N_GRAPHS, 4), 64, 0, stream>>>(h1b, gstart, gbuf);

    // fc1: [64,512]@[512,1024] split-K=4 -> part1 ; reduce + b1 + relu -> fc1o
    dim3 gfc1((D_FC + 63) / 64, 1, S1);
    gemm_splitk<<<gfc1, 256, 0, stream>>>(gbuf, W1, part1, N_GRAPHS, D_FC, D_H, D_H / S1);
    reduce_bias_relu<<<(N_GRAPHS * D_FC + 255) / 256, 256, 0, stream>>>(
        part1, b1, fc1o, N_GRAPHS * D_FC, D_FC, S1);

    // fc2: [64,1024]@[1024,5000] split-K=8 -> part2 ; reduce + BN + sigmoid -> out
    dim3 gfc2((OUT_DIMS + 63) / 64, 1, S2);
    gemm_splitk<<<gfc2, 256, 0, stream>>>(fc1o, W2, part2, N_GRAPHS, OUT_DIMS, D_FC, D_FC / S2);
    reduce_bn_sigmoid<<<(N_GRAPHS * OUT_DIMS + 255) / 256, 256, 0, stream>>>(
        part2, b2, gamma, beta, out, S2);
}

// Round 9
// 522.287 us; speedup vs baseline: 1.8149x; 1.0326x over previous
//
#include <hip/hip_runtime.h>
#include <math.h>

#define N_NODES 20000
#define N_EDGES 320000
#define N_GRAPHS 64
#define D_IN 1280
#define D_H 512
#define D_FC 1024
#define OUT_DIMS 5000

typedef unsigned short ushort_t;
typedef short bf16x8 __attribute__((ext_vector_type(8)));
typedef float f32x4 __attribute__((ext_vector_type(4)));

__device__ __forceinline__ ushort_t f2b(float x) {
    unsigned u = __float_as_uint(x);
    unsigned r = (u + 0x7FFFu + ((u >> 16) & 1u)) >> 16;  // RNE
    return (ushort_t)r;
}

// async 16B global->LDS DMA: per-lane gptr, wave-uniform LDS base + lane*16
#define GLL16(gp, lp)                                                                  \
    __builtin_amdgcn_global_load_lds((const __attribute__((address_space(1))) void*)(gp), \
                                     (__attribute__((address_space(3))) void*)(lp), 16, 0, 0)

// XCD swizzle for conv GEMMs: grid (32, 20) -> f in [0,640)
// rt = (f>>5)*8 + (f&7), ct = (f&31)>>3 ; 4 col-tiles of a row-tile share f%8 (same XCD)
#define CONV_SWIZZLE()                                         \
    const int f = blockIdx.y * 32 + blockIdx.x;                \
    const int rt = (f >> 5) * 8 + (f & 7);                     \
    const int ct = (f & 31) >> 3;                              \
    const int rowBase = rt * 128;                              \
    const int colBase = ct * 128;                              \
    if (rowBase >= M) return;

// ============ bf16 MFMA GEMM, double-buffered DMA staging ============
// C[M,N] = A[M,K] @ BT[N,K]^T. 128x128 tile, 4 waves (64x64 each), BK=32.
// LDS layout XOR-swizzled: 16B chunk q of row r lives at slot q^((r>>1)&3)
// -> frag ds_read_b128 is 2-way bank aliased (free), and the layout is
// expressible by global_load_lds (lane picks the matching global chunk).
// Prefetch distance 2: tile k+2's DMAs issue after the reads-done barrier,
// overlapping the MFMA phase; __syncthreads provides all ordering.
__global__ __launch_bounds__(256) void mfma_gemm_db(const ushort_t* __restrict__ A,
                                                    const ushort_t* __restrict__ BT,
                                                    ushort_t* __restrict__ C,
                                                    int M, int N, int K) {
    __shared__ ushort_t lds[4 * 4096];  // As0, As1, Bs0, Bs1 (8 KB each)
    const int t = threadIdx.x;
    const int lane = t & 63, wave = t >> 6;
    const int wrow = (wave >> 1) * 64, wcol = (wave & 1) * 64;
    const int lo = lane & 15, quad = lane >> 4;
    CONV_SWIZZLE();

    // DMA sources: slot s -> row r=s>>2, slot_q=s&3, global chunk q=slot_q^((r>>1)&3)
    const int s0 = t, s1 = t + 256;
    const int r0 = s0 >> 2, r1 = s1 >> 2;
    const int q0 = (s0 & 3) ^ ((r0 >> 1) & 3);
    const int q1 = (s1 & 3) ^ ((r1 >> 1) & 3);
    int ar0 = rowBase + r0; if (ar0 >= M) ar0 = M - 1;  // clamp; garbage rows never stored
    int ar1 = rowBase + r1; if (ar1 >= M) ar1 = M - 1;
    const ushort_t* pa0 = A + (size_t)ar0 * K + q0 * 8;
    const ushort_t* pa1 = A + (size_t)ar1 * K + q1 * 8;
    const ushort_t* pb0 = BT + (size_t)(colBase + r0) * K + q0 * 8;
    const ushort_t* pb1 = BT + (size_t)(colBase + r1) * K + q1 * 8;

    // issue one full tile (A+B) into buffer p, then advance pointers
#define ISSUE_TILE(p)                                                  \
    {                                                                  \
        GLL16(pa0, lds + (p) * 4096 + wave * 512);                     \
        GLL16(pa1, lds + (p) * 4096 + 2048 + wave * 512);              \
        GLL16(pb0, lds + 8192 + (p) * 4096 + wave * 512);              \
        GLL16(pb1, lds + 8192 + (p) * 4096 + 2048 + wave * 512);       \
        pa0 += 32; pa1 += 32; pb0 += 32; pb1 += 32;                    \
    }

    // frag LDS offsets (ushort units), loop-invariant
    const int qs = (quad ^ ((lo >> 1) & 3)) * 8;
    int offA[4], offB[4];
#pragma unroll
    for (int i = 0; i < 4; ++i) offA[i] = (wrow + i * 16 + lo) * 32 + qs;
#pragma unroll
    for (int j = 0; j < 4; ++j) offB[j] = (wcol + j * 16 + lo) * 32 + qs;

    f32x4 acc[4][4] = {};
    const int NK = K >> 5;

    ISSUE_TILE(0);
    if (NK > 1) ISSUE_TILE(1);

    for (int k = 0; k < NK; ++k) {
        __syncthreads();  // drains DMAs: tile k (and k+1) landed everywhere
        const ushort_t* Ab = lds + (k & 1) * 4096;
        const ushort_t* Bb = lds + 8192 + (k & 1) * 4096;
        bf16x8 af[4], bfr[4];
#pragma unroll
        for (int i = 0; i < 4; ++i) af[i] = *(const bf16x8*)&Ab[offA[i]];
#pragma unroll
        for (int j = 0; j < 4; ++j) bfr[j] = *(const bf16x8*)&Bb[offB[j]];
        __syncthreads();  // all waves' frag reads done -> buf[k&1] reusable
        if (k + 2 < NK) ISSUE_TILE(k & 1);  // flies during MFMA phase
#pragma unroll
        for (int i = 0; i < 4; ++i)
#pragma unroll
            for (int j = 0; j < 4; ++j)
                acc[i][j] = __builtin_amdgcn_mfma_f32_16x16x32_bf16(af[i], bfr[j], acc[i][j], 0, 0, 0);
    }
#undef ISSUE_TILE

    // epilogue: C/D layout col=lane&15, row=quad*4+reg ; store bf16
#pragma unroll
    for (int i = 0; i < 4; ++i) {
        int row0 = rowBase + wrow + i * 16 + quad * 4;
#pragma unroll
        for (int j = 0; j < 4; ++j) {
            int col = colBase + wcol + j * 16 + lo;
            if (col >= N) continue;
#pragma unroll
            for (int r = 0; r < 4; ++r) {
                int row = row0 + r;
                if (row < M) C[(size_t)row * N + col] = f2b(acc[i][j][r]);
            }
        }
    }
}

// fp32 -> bf16 bulk convert (8 elems/thread)
__global__ void cvt_f32_bf16(const float* __restrict__ X, ushort_t* __restrict__ Y, int n8) {
    int i = blockIdx.x * blockDim.x + threadIdx.x;
    if (i >= n8) return;
    const float4* p = (const float4*)(X + (size_t)i * 8);
    float4 v0 = p[0], v1 = p[1];
    ushort_t w[8] = {f2b(v0.x), f2b(v0.y), f2b(v0.z), f2b(v0.w),
                     f2b(v1.x), f2b(v1.y), f2b(v1.z), f2b(v1.w)};
    *(uint4*)(Y + (size_t)i * 8) = *(uint4*)w;
}

// transpose + fp32->bf16: WT[n*K+k] = bf16(W[k*N+n])
__global__ void wt_cvt_transpose(const float* __restrict__ W, ushort_t* __restrict__ WT,
                                 int K, int N) {
    int i = blockIdx.x * blockDim.x + threadIdx.x;
    if (i >= N * K) return;
    int n = i / K, k = i - n * K;
    WT[i] = f2b(W[(size_t)k * N + n]);
}

// ---------------- fp32 split-K tiled GEMM (FC head) ----------------
__global__ __launch_bounds__(256) void gemm_splitk(const float* __restrict__ A,
                                                   const float* __restrict__ B,
                                                   float* __restrict__ P,
                                                   int M, int N, int K, int KC) {
    __shared__ float As[16][64];
    __shared__ float Bs[16][64];
    const int t = threadIdx.x;
    const int tx = t & 15, ty = t >> 4;
    const int rowBase = blockIdx.y * 64;
    const int colBase = blockIdx.x * 64;
    const int kbeg = blockIdx.z * KC;
    const int kend = kbeg + KC;
    float acc[4][4] = {};
    for (int k0 = kbeg; k0 < kend; k0 += 16) {
#pragma unroll
        for (int i = 0; i < 4; ++i) {
            int idx = t + i * 256;
            int row = idx >> 4, kk = idx & 15;
            int gr = rowBase + row;
            As[kk][row] = (gr < M) ? A[(size_t)gr * K + k0 + kk] : 0.f;
        }
#pragma unroll
        for (int i = 0; i < 4; ++i) {
            int idx = t + i * 256;
            int kk = idx >> 6, col = idx & 63;
            int gc = colBase + col;
            Bs[kk][col] = (gc < N) ? B[(size_t)(k0 + kk) * N + gc] : 0.f;
        }
        __syncthreads();
#pragma unroll
        for (int kk = 0; kk < 16; ++kk) {
            float a[4], b[4];
#pragma unroll
            for (int i = 0; i < 4; ++i) a[i] = As[kk][ty * 4 + i];
#pragma unroll
            for (int j = 0; j < 4; ++j) b[j] = Bs[kk][tx * 4 + j];
#pragma unroll
            for (int i = 0; i < 4; ++i)
#pragma unroll
                for (int j = 0; j < 4; ++j) acc[i][j] = fmaf(a[i], b[j], acc[i][j]);
        }
        __syncthreads();
    }
    float* Pz = P + (size_t)blockIdx.z * M * N;
#pragma unroll
    for (int i = 0; i < 4; ++i) {
        int gr = rowBase + ty * 4 + i;
        if (gr >= M) continue;
#pragma unroll
        for (int j = 0; j < 4; ++j) {
            int gc = colBase + tx * 4 + j;
            if (gc < N) Pz[(size_t)gr * N + gc] = acc[i][j];
        }
    }
}

// fc1 reduce: out = relu(sum_z P[z] + b)
__global__ void reduce_bias_relu(const float* __restrict__ P, const float* __restrict__ b,
                                 float* __restrict__ out, int total, int N, int S) {
    int i = blockIdx.x * blockDim.x + threadIdx.x;
    if (i >= total) return;
    float s = 0.f;
    for (int z = 0; z < S; ++z) s += P[(size_t)z * total + i];
    out[i] = fmaxf(s + b[i % N], 0.f);
}

// fc2 reduce: out = sigmoid((sum_z P[z] + b2) * gamma/sqrt(1+eps) + beta)
__global__ void reduce_bn_sigmoid(const float* __restrict__ P, const float* __restrict__ b2,
                                  const float* __restrict__ gamma, const float* __restrict__ beta,
                                  float* __restrict__ out, int S) {
    int i = blockIdx.x * blockDim.x + threadIdx.x;
    if (i >= N_GRAPHS * OUT_DIMS) return;
    int c = i % OUT_DIMS;
    float s = 0.f;
    for (int z = 0; z < S; ++z) s += P[(size_t)z * N_GRAPHS * OUT_DIMS + i];
    const float sc = 0.9999950000374997f;  // 1/sqrt(1+1e-5)
    float zz = (s + b2[c]) * (gamma[c] * sc) + beta[c];
    out[i] = 1.f / (1.f + expf(-zz));
}

// ---------------- CSR construction ----------------
__global__ void hist_deg(const int* __restrict__ dst, int* __restrict__ cnt) {
    int e = blockIdx.x * blockDim.x + threadIdx.x;
    if (e < N_EDGES) atomicAdd(cnt + dst[e], 1);
}

__global__ void compute_dinv(const int* __restrict__ cnt, float* __restrict__ dinv) {
    int v = blockIdx.x * blockDim.x + threadIdx.x;
    if (v < N_NODES) dinv[v] = rsqrtf((float)cnt[v] + 1.0f);  // +1 self-loop
}

__global__ __launch_bounds__(256) void scan_rowptr(const int* __restrict__ cnt,
                                                   int* __restrict__ rowptr) {
    __shared__ int sums[256];
    const int t = threadIdx.x;
    const int CH = (N_NODES + 255) / 256;
    const int base = t * CH;
    int s = 0;
    for (int i = 0; i < CH; ++i) {
        int v = base + i;
        if (v < N_NODES) s += cnt[v];
    }
    sums[t] = s;
    __syncthreads();
    for (int off = 1; off < 256; off <<= 1) {
        int y = (t >= off) ? sums[t - off] : 0;
        __syncthreads();
        sums[t] += y;
        __syncthreads();
    }
    int run = sums[t] - s;
    for (int i = 0; i < CH; ++i) {
        int v = base + i;
        if (v < N_NODES) {
            rowptr[v] = run;
            run += cnt[v];
        }
    }
    if (t == 255) rowptr[N_NODES] = run;
}

__global__ void fill_csr(const int* __restrict__ src, const int* __restrict__ dst,
                         const int* __restrict__ rowptr, int* __restrict__ cursor,
                         int* __restrict__ col) {
    int e = blockIdx.x * blockDim.x + threadIdx.x;
    if (e < N_EDGES) {
        int d = dst[e];
        int p = rowptr[d] + atomicAdd(cursor + d, 1);
        col[p] = src[e];
    }
}

// ---------------- bf16 gather-aggregate ----------------
__device__ __forceinline__ void bf8_fma(uint4 v, float c, float* acc) {
    unsigned a[4] = {v.x, v.y, v.z, v.w};
#pragma unroll
    for (int i = 0; i < 4; ++i) {
        float lo = __uint_as_float(a[i] << 16);
        float hi = __uint_as_float(a[i] & 0xFFFF0000u);
        acc[2 * i]     = fmaf(lo, c, acc[2 * i]);
        acc[2 * i + 1] = fmaf(hi, c, acc[2 * i + 1]);
    }
}

__device__ __forceinline__ void agg_node_bf16(const ushort_t* __restrict__ H,
                                              const int* __restrict__ rowptr,
                                              const int* __restrict__ col,
                                              const float* __restrict__ dinv,
                                              const float* __restrict__ bias,
                                              int v, int f, float* r) {
    const int beg = rowptr[v], end = rowptr[v + 1];
    const float dv = dinv[v];
    float acc[8] = {};
    int j = beg;
    for (; j + 3 < end; j += 4) {
        int s0 = col[j], s1 = col[j + 1], s2 = col[j + 2], s3 = col[j + 3];
        float c0 = dinv[s0] * dv, c1 = dinv[s1] * dv;
        float c2 = dinv[s2] * dv, c3 = dinv[s3] * dv;
        uint4 h0 = *(const uint4*)(H + (size_t)s0 * D_H + f);
        uint4 h1 = *(const uint4*)(H + (size_t)s1 * D_H + f);
        uint4 h2 = *(const uint4*)(H + (size_t)s2 * D_H + f);
        uint4 h3 = *(const uint4*)(H + (size_t)s3 * D_H + f);
        bf8_fma(h0, c0, acc);
        bf8_fma(h1, c1, acc);
        bf8_fma(h2, c2, acc);
        bf8_fma(h3, c3, acc);
    }
    for (; j < end; ++j) {
        int s0 = col[j];
        float c0 = dinv[s0] * dv;
        uint4 h0 = *(const uint4*)(H + (size_t)s0 * D_H + f);
        bf8_fma(h0, c0, acc);
    }
    uint4 hv = *(const uint4*)(H + (size_t)v * D_H + f);
    bf8_fma(hv, dv * dv, acc);  // self-loop
    float4 b0 = *(const float4*)(bias + f);
    float4 b1 = *(const float4*)(bias + f + 4);
    r[0] = fmaxf(acc[0] + b0.x, 0.f);
    r[1] = fmaxf(acc[1] + b0.y, 0.f);
    r[2] = fmaxf(acc[2] + b0.z, 0.f);
    r[3] = fmaxf(acc[3] + b0.w, 0.f);
    r[4] = fmaxf(acc[4] + b1.x, 0.f);
    r[5] = fmaxf(acc[5] + b1.y, 0.f);
    r[6] = fmaxf(acc[6] + b1.z, 0.f);
    r[7] = fmaxf(acc[7] + b1.w, 0.f);
}

__global__ __launch_bounds__(64) void gather_agg_relu_bf16(const ushort_t* __restrict__ H,
                                                           const int* __restrict__ rowptr,
                                                           const int* __restrict__ col,
                                                           const float* __restrict__ dinv,
                                                           const float* __restrict__ bias,
                                                           ushort_t* __restrict__ out) {
    const int v = blockIdx.x;
    const int f = threadIdx.x * 8;
    float r[8];
    agg_node_bf16(H, rowptr, col, dinv, bias, v, f, r);
    ushort_t o[8];
#pragma unroll
    for (int i = 0; i < 8; ++i) o[i] = f2b(r[i]);
    *(uint4*)(out + (size_t)v * D_H + f) = *(uint4*)o;
}

// ---------------- segment max pool (batch is sorted; no atomics) ----------------
__global__ void graph_bounds(const int* __restrict__ batch, int* __restrict__ gstart) {
    int g = threadIdx.x;
    if (g > N_GRAPHS) return;
    int lo = 0, hi = N_NODES;
    while (lo < hi) {
        int mid = (lo + hi) >> 1;
        if (batch[mid] < g) lo = mid + 1; else hi = mid;
    }
    gstart[g] = lo;
}

__global__ __launch_bounds__(64) void pool_max_seg(const ushort_t* __restrict__ h2,
                                                   const int* __restrict__ gstart,
                                                   float* __restrict__ gbuf) {
    const int g = blockIdx.x;
    const int f = blockIdx.y * 128 + threadIdx.x * 2;
    const int beg = gstart[g], end = gstart[g + 1];
    float m0 = -INFINITY, m1 = -INFINITY;
    int v = beg;
    for (; v + 3 < end; v += 4) {
        unsigned u0 = *(const unsigned*)(h2 + (size_t)(v + 0) * D_H + f);
        unsigned u1 = *(const unsigned*)(h2 + (size_t)(v + 1) * D_H + f);
        unsigned u2 = *(const unsigned*)(h2 + (size_t)(v + 2) * D_H + f);
        unsigned u3 = *(const unsigned*)(h2 + (size_t)(v + 3) * D_H + f);
        m0 = fmaxf(m0, fmaxf(fmaxf(__uint_as_float(u0 << 16), __uint_as_float(u1 << 16)),
                             fmaxf(__uint_as_float(u2 << 16), __uint_as_float(u3 << 16))));
        m1 = fmaxf(m1, fmaxf(fmaxf(__uint_as_float(u0 & 0xFFFF0000u), __uint_as_float(u1 & 0xFFFF0000u)),
                             fmaxf(__uint_as_float(u2 & 0xFFFF0000u), __uint_as_float(u3 & 0xFFFF0000u))));
    }
    for (; v < end; ++v) {
        unsigned u = *(const unsigned*)(h2 + (size_t)v * D_H + f);
        m0 = fmaxf(m0, __uint_as_float(u << 16));
        m1 = fmaxf(m1, __uint_as_float(u & 0xFFFF0000u));
    }
    gbuf[g * D_H + f] = m0;
    gbuf[g * D_H + f + 1] = m1;
}

extern "C" void kernel_launch(void* const* d_in, const int* in_sizes, int n_in,
                              void* d_out, int out_size, void* d_ws, size_t ws_size,
                              hipStream_t stream) {
    const float* x     = (const float*)d_in[0];
    const int*   ei    = (const int*)d_in[1];    // int64 in reference -> int32 on device
    const int*   batch = (const int*)d_in[2];
    const float* Wg1   = (const float*)d_in[3];
    const float* bg1   = (const float*)d_in[4];
    const float* Wg2   = (const float*)d_in[5];
    const float* bg2   = (const float*)d_in[6];
    const float* W1    = (const float*)d_in[7];
    const float* b1    = (const float*)d_in[8];
    const float* W2    = (const float*)d_in[9];
    const float* b2    = (const float*)d_in[10];
    const float* gamma = (const float*)d_in[11];
    const float* beta  = (const float*)d_in[12];
    const int* src = ei;
    const int* dst = ei + N_EDGES;
    float* out = (float*)d_out;

    const int S1 = 4;  // fc1 K-split (K=512, KC=128)
    const int S2 = 8;  // fc2 K-split (K=1024, KC=128)

    // workspace layout (all 16B-aligned)
    ushort_t* hpre   = (ushort_t*)d_ws;                        // [N_NODES, D_H] bf16 (conv GEMM out)
    ushort_t* h1b    = hpre + (size_t)N_NODES * D_H;           // [N_NODES, D_H] bf16 (h1; reused as h2)
    ushort_t* w1t    = h1b + (size_t)N_NODES * D_H;            // [D_H, D_IN] bf16 (Wg1^T)
    ushort_t* w2t    = w1t + (size_t)D_H * D_IN;               // [D_H, D_H] bf16 (Wg2^T)
    ushort_t* xb     = w2t + (size_t)D_H * D_H;                // [N_NODES, D_IN] bf16 (x)
    float*    dinv   = (float*)(xb + (size_t)N_NODES * D_IN);  // [N_NODES]
    float*    gbuf   = dinv + N_NODES;                         // [N_GRAPHS, D_H]
    float*    fc1o   = gbuf + N_GRAPHS * D_H;                  // [N_GRAPHS, D_FC]
    float*    part1  = fc1o + N_GRAPHS * D_FC;                 // [S1, 64, D_FC]
    float*    part2  = part1 + (size_t)S1 * N_GRAPHS * D_FC;   // [S2, 64, OUT_DIMS]
    int*      cnt    = (int*)(part2 + (size_t)S2 * N_GRAPHS * OUT_DIMS);  // [N_NODES]
    int*      rowptr = cnt + N_NODES;                          // [N_NODES+1]
    int*      cursor = rowptr + N_NODES + 1;                   // [N_NODES]
    int*      colidx = cursor + N_NODES;                       // [N_EDGES]
    int*      gstart = colidx + N_EDGES;                       // [N_GRAPHS+1]

    // ---- CSR build + dinv + weight transpose/convert + x convert + graph bounds ----
    hipMemsetAsync(cnt, 0, N_NODES * sizeof(int), stream);
    hipMemsetAsync(cursor, 0, N_NODES * sizeof(int), stream);
    hist_deg<<<(N_EDGES + 255) / 256, 256, 0, stream>>>(dst, cnt);
    compute_dinv<<<(N_NODES + 255) / 256, 256, 0, stream>>>(cnt, dinv);
    scan_rowptr<<<1, 256, 0, stream>>>(cnt, rowptr);
    fill_csr<<<(N_EDGES + 255) / 256, 256, 0, stream>>>(src, dst, rowptr, cursor, colidx);
    wt_cvt_transpose<<<(D_H * D_IN + 255) / 256, 256, 0, stream>>>(Wg1, w1t, D_IN, D_H);
    wt_cvt_transpose<<<(D_H * D_H + 255) / 256, 256, 0, stream>>>(Wg2, w2t, D_H, D_H);
    cvt_f32_bf16<<<(N_NODES * D_IN / 8 + 255) / 256, 256, 0, stream>>>(x, xb, N_NODES * D_IN / 8);
    graph_bounds<<<1, N_GRAPHS + 1, 0, stream>>>(batch, gstart);

    dim3 gconv(32, 20);  // swizzled: 640 slots, 628 active (157 row-tiles x 4 col-tiles)

    // conv1: hpre = bf16(xb @ Wg1) ; gather+relu -> h1b (bf16)
    mfma_gemm_db<<<gconv, 256, 0, stream>>>(xb, w1t, hpre, N_NODES, D_H, D_IN);
    gather_agg_relu_bf16<<<N_NODES, 64, 0, stream>>>(hpre, rowptr, colidx, dinv, bg1, h1b);

    // conv2: hpre = bf16(h1b @ Wg2) ; gather+relu -> h2 (reuse h1b) ; segment pool
    mfma_gemm_db<<<gconv, 256, 0, stream>>>(h1b, w2t, hpre, N_NODES, D_H, D_H);
    gather_agg_relu_bf16<<<N_NODES, 64, 0, stream>>>(hpre, rowptr, colidx, dinv, bg2, h1b);
    pool_max_seg<<<dim3(N_GRAPHS, 4), 64, 0, stream>>>(h1b, gstart, gbuf);

    // fc1: [64,512]@[512,1024] split-K=4 -> part1 ; reduce + b1 + relu -> fc1o
    dim3 gfc1((D_FC + 63) / 64, 1, S1);
    gemm_splitk<<<gfc1, 256, 0, stream>>>(gbuf, W1, part1, N_GRAPHS, D_FC, D_H, D_H / S1);
    reduce_bias_relu<<<(N_GRAPHS * D_FC + 255) / 256, 256, 0, stream>>>(
        part1, b1, fc1o, N_GRAPHS * D_FC, D_FC, S1);

    // fc2: [64,1024]@[1024,5000] split-K=8 -> part2 ; reduce + BN + sigmoid -> out
    dim3 gfc2((OUT_DIMS + 63) / 64, 1, S2);
    gemm_splitk<<<gfc2, 256, 0, stream>>>(fc1o, W2, part2, N_GRAPHS, OUT_DIMS, D_FC, D_FC / S2);
    reduce_bn_sigmoid<<<(N_GRAPHS * OUT_DIMS + 255) / 256, 256, 0, stream>>>(
        part2, b2, gamma, beta, out, S2);
}